// Round 4
// baseline (2827.240 us; speedup 1.0000x reference)
//
#include <hip/hip_runtime.h>
#include <hip/hip_bf16.h>

typedef unsigned short u16;
typedef __bf16 bf16x8 __attribute__((ext_vector_type(8)));
typedef float f32x4 __attribute__((ext_vector_type(4)));
typedef unsigned short u16x8 __attribute__((ext_vector_type(8)));

constexpr int DIMC = 2048;
constexpr int SEQ = 2048;
constexpr int NHEAD = 16;
constexpr int HDIM = 128;
constexpr int NEXP = 4;
constexpr int HIDC = 5632;
constexpr int HSH = 2816;  // == HIDC/2
constexpr int MOD6 = 6 * DIMC;

static __device__ __forceinline__ u16 f2bf(float f) {
  __hip_bfloat16 b = __float2bfloat16(f);
  return __builtin_bit_cast(u16, b);
}
static __device__ __forceinline__ float bf2f(u16 u) {
  unsigned int x = ((unsigned int)u) << 16;
  return __builtin_bit_cast(float, x);
}
static __device__ __forceinline__ float sigf(float x) { return 1.f / (1.f + __expf(-x)); }

static __device__ __forceinline__ void gload16(const void* src, void* dst) {
  __builtin_amdgcn_global_load_lds((const __attribute__((address_space(1))) void*)src,
                                   (__attribute__((address_space(3))) void*)dst, 16, 0, 0);
}

// split f32 8-vector (two f32x4) into hi/lo bf16x8: v ≈ h + l, |l| <= ulp(h)/2
static __device__ __forceinline__ void split44(f32x4 lo, f32x4 hi, bf16x8& h, bf16x8& l) {
#pragma unroll
  for (int e = 0; e < 4; ++e) {
    float f0 = lo[e];
    u16 h0 = f2bf(f0);
    h[e] = __builtin_bit_cast(__bf16, h0);
    l[e] = __builtin_bit_cast(__bf16, f2bf(f0 - bf2f(h0)));
    float f1 = hi[e];
    u16 h1 = f2bf(f1);
    h[4 + e] = __builtin_bit_cast(__bf16, h1);
    l[4 + e] = __builtin_bit_cast(__bf16, f2bf(f1 - bf2f(h1)));
  }
}

// block = 256 threads (4 waves); returns total across block to all threads
static __device__ __forceinline__ float blockSum(float v) {
#pragma unroll
  for (int m = 1; m < 64; m <<= 1) v += __shfl_xor(v, m);
  __shared__ float s[4];
  int w = threadIdx.x >> 6;
  if ((threadIdx.x & 63) == 0) s[w] = v;
  __syncthreads();
  float r = s[0] + s[1] + s[2] + s[3];
  __syncthreads();
  return r;
}

// ---------------- transpose f32 [R,C] (row stride ldin) -> bf16 [C,R] ----------------
__global__ __launch_bounds__(256) void k_transpose(const float* __restrict__ in, u16* __restrict__ out,
                                                   int R, int C, int ldin) {
  __shared__ __align__(16) float tile[32][33];
  int tx = threadIdx.x & 31, ty = threadIdx.x >> 5;
  int c0 = blockIdx.x * 32, r0 = blockIdx.y * 32;
#pragma unroll
  for (int i = 0; i < 32; i += 8)
    tile[ty + i][tx] = in[(size_t)(r0 + ty + i) * ldin + c0 + tx];
  __syncthreads();
#pragma unroll
  for (int i = 0; i < 32; i += 8)
    out[(size_t)(c0 + ty + i) * R + r0 + tx] = f2bf(tile[tx][ty + i]);
}

// ---------------- transpose f32 [R,C] -> f32 [C,R] (attention weights) ----------------
__global__ __launch_bounds__(256) void k_transpose_f(const float* __restrict__ in, float* __restrict__ out,
                                                     int R, int C, int ldin) {
  __shared__ __align__(16) float tile[32][33];
  int tx = threadIdx.x & 31, ty = threadIdx.x >> 5;
  int c0 = blockIdx.x * 32, r0 = blockIdx.y * 32;
#pragma unroll
  for (int i = 0; i < 32; i += 8)
    tile[ty + i][tx] = in[(size_t)(r0 + ty + i) * ldin + c0 + tx];
  __syncthreads();
#pragma unroll
  for (int i = 0; i < 32; i += 8)
    out[(size_t)(c0 + ty + i) * R + r0 + tx] = tile[tx][ty + i];
}

// ---------------- adaLN: mod = silu(a) @ W_ada + b_ada, split over 16 d-slices ----------------
__global__ __launch_bounds__(256) void k_adaln_p(const float* __restrict__ a, const float* __restrict__ W,
                                                 float* __restrict__ partial) {
  __shared__ float sa[128];
  int tid = threadIdx.x, slice = blockIdx.y;
  if (tid < 128) { float v = a[slice * 128 + tid]; sa[tid] = v * sigf(v); }
  __syncthreads();
  int j = blockIdx.x * 256 + tid;
  float acc = 0.f;
#pragma unroll 4
  for (int d = 0; d < 128; ++d) acc += sa[d] * W[(size_t)(slice * 128 + d) * MOD6 + j];
  partial[(size_t)slice * MOD6 + j] = acc;
}
__global__ __launch_bounds__(256) void k_adaln_r(const float* __restrict__ partial, const float* __restrict__ b,
                                                 float* __restrict__ mod) {
  int j = blockIdx.x * 256 + threadIdx.x;
  float acc = b[j];
#pragma unroll
  for (int s = 0; s < 16; ++s) acc += partial[(size_t)s * MOD6 + j];
  mod[j] = acc;
}

// ---------------- LayerNorm + adaLN modulate -> f32 (attention x) ----------------
__global__ __launch_bounds__(256) void k_ln_modf(const float* __restrict__ X, const float* __restrict__ mod,
                                                 int shOff, int scOff, float* __restrict__ out) {
  int row = blockIdx.x, tid = threadIdx.x;
  const float4* x4 = (const float4*)(X + (size_t)row * DIMC);
  float4 v0 = x4[tid * 2], v1 = x4[tid * 2 + 1];
  float s = v0.x + v0.y + v0.z + v0.w + v1.x + v1.y + v1.z + v1.w;
  float ss = v0.x * v0.x + v0.y * v0.y + v0.z * v0.z + v0.w * v0.w +
             v1.x * v1.x + v1.y * v1.y + v1.z * v1.z + v1.w * v1.w;
  s = blockSum(s);
  ss = blockSum(ss);
  float mean = s * (1.f / DIMC);
  float var = ss * (1.f / DIMC) - mean * mean;
  float rstd = rsqrtf(var + 1e-6f);
  const float* sh = mod + shOff;
  const float* sc = mod + scOff;
  int c = tid * 8;
  float xv[8] = {v0.x, v0.y, v0.z, v0.w, v1.x, v1.y, v1.z, v1.w};
  float4 o0, o1;
  float ov[8];
#pragma unroll
  for (int e = 0; e < 8; ++e) ov[e] = (xv[e] - mean) * rstd * (1.f + sc[c + e]) + sh[c + e];
  o0.x = ov[0]; o0.y = ov[1]; o0.z = ov[2]; o0.w = ov[3];
  o1.x = ov[4]; o1.y = ov[5]; o1.z = ov[6]; o1.w = ov[7];
  float4* y4 = (float4*)(out + (size_t)row * DIMC);
  y4[tid * 2] = o0;
  y4[tid * 2 + 1] = o1;
}

// ---------------- LayerNorm + adaLN modulate -> bf16 (MoE x_act) ----------------
__global__ __launch_bounds__(256) void k_ln_mod(const float* __restrict__ X, const float* __restrict__ mod,
                                                int shOff, int scOff, u16* __restrict__ out) {
  int row = blockIdx.x, tid = threadIdx.x;
  const float4* x4 = (const float4*)(X + (size_t)row * DIMC);
  float4 v0 = x4[tid * 2], v1 = x4[tid * 2 + 1];
  float s = v0.x + v0.y + v0.z + v0.w + v1.x + v1.y + v1.z + v1.w;
  float ss = v0.x * v0.x + v0.y * v0.y + v0.z * v0.z + v0.w * v0.w +
             v1.x * v1.x + v1.y * v1.y + v1.z * v1.z + v1.w * v1.w;
  s = blockSum(s);
  ss = blockSum(ss);
  float mean = s * (1.f / DIMC);
  float var = ss * (1.f / DIMC) - mean * mean;
  float rstd = rsqrtf(var + 1e-6f);
  const float* sh = mod + shOff;
  const float* sc = mod + scOff;
  int c = tid * 8;
  float xv[8] = {v0.x, v0.y, v0.z, v0.w, v1.x, v1.y, v1.z, v1.w};
  u16x8 o;
#pragma unroll
  for (int e = 0; e < 8; ++e) o[e] = f2bf((xv[e] - mean) * rstd * (1.f + sc[c + e]) + sh[c + e]);
  *(u16x8*)(out + (size_t)row * DIMC + c) = o;
}

// ---------------- RMSNorm f32 in -> f32 out, * weight * scale ----------------
__global__ __launch_bounds__(256) void k_rms_f32(const float* __restrict__ X, const float* __restrict__ w,
                                                 float scale, float* __restrict__ out) {
  int row = blockIdx.x, tid = threadIdx.x;
  const float4* x4 = (const float4*)(X + (size_t)row * DIMC);
  float4 v0 = x4[tid * 2], v1 = x4[tid * 2 + 1];
  float ss = v0.x * v0.x + v0.y * v0.y + v0.z * v0.z + v0.w * v0.w +
             v1.x * v1.x + v1.y * v1.y + v1.z * v1.z + v1.w * v1.w;
  ss = blockSum(ss);
  float rstd = rsqrtf(ss * (1.f / DIMC) + 1e-5f) * scale;
  int c = tid * 8;
  float xv[8] = {v0.x, v0.y, v0.z, v0.w, v1.x, v1.y, v1.z, v1.w};
  float ov[8];
#pragma unroll
  for (int e = 0; e < 8; ++e) ov[e] = xv[e] * rstd * w[c + e];
  float4 o0 = {ov[0], ov[1], ov[2], ov[3]}, o1 = {ov[4], ov[5], ov[6], ov[7]};
  float4* y4 = (float4*)(out + (size_t)row * DIMC);
  y4[tid * 2] = o0;
  y4[tid * 2 + 1] = o1;
}

// ---------------- gating: recompute LN+mod in f32, softmax over 4, top-2 -> comb[n][4] ----------------
__global__ __launch_bounds__(256) void k_gate(const float* __restrict__ img, const float* __restrict__ mod,
                                              const float* __restrict__ gw, float* __restrict__ comb) {
  int n = blockIdx.x, tid = threadIdx.x;
  const float4* x4 = (const float4*)(img + (size_t)n * DIMC);
  float4 v0 = x4[tid * 2], v1 = x4[tid * 2 + 1];
  float s = v0.x + v0.y + v0.z + v0.w + v1.x + v1.y + v1.z + v1.w;
  float ss = v0.x * v0.x + v0.y * v0.y + v0.z * v0.z + v0.w * v0.w +
             v1.x * v1.x + v1.y * v1.y + v1.z * v1.z + v1.w * v1.w;
  s = blockSum(s);
  ss = blockSum(ss);
  float mean = s * (1.f / DIMC);
  float var = ss * (1.f / DIMC) - mean * mean;
  float rstd = rsqrtf(var + 1e-6f);
  const float* sh = mod + 3 * DIMC;
  const float* sc = mod + 4 * DIMC;
  int c = tid * 8;
  float xv[8] = {v0.x, v0.y, v0.z, v0.w, v1.x, v1.y, v1.z, v1.w};
  float y[8];
#pragma unroll
  for (int e = 0; e < 8; ++e) y[e] = (xv[e] - mean) * rstd * (1.f + sc[c + e]) + sh[c + e];
  float accs[NEXP];
#pragma unroll
  for (int ex = 0; ex < NEXP; ++ex) {
    float a = 0.f;
#pragma unroll
    for (int e = 0; e < 8; ++e) a += y[e] * gw[(size_t)ex * DIMC + c + e];
    accs[ex] = blockSum(a);
  }
  if (tid == 0) {
    float mx = fmaxf(fmaxf(accs[0], accs[1]), fmaxf(accs[2], accs[3]));
    float ex0 = __expf(accs[0] - mx), ex1 = __expf(accs[1] - mx);
    float ex2 = __expf(accs[2] - mx), ex3 = __expf(accs[3] - mx);
    float inv = 1.f / (ex0 + ex1 + ex2 + ex3);
    float v[4] = {ex0 * inv, ex1 * inv, ex2 * inv, ex3 * inv};
    int i1 = 0;
    for (int e = 1; e < 4; ++e)
      if (v[e] > v[i1]) i1 = e;
    int i2 = -1;
    for (int e = 0; e < 4; ++e) {
      if (e == i1) continue;
      if (i2 < 0 || v[e] > v[i2]) i2 = e;
    }
    for (int e = 0; e < 4; ++e) comb[(size_t)n * 4 + e] = (e == i1 || e == i2) ? v[e] : 0.f;
  }
}

// ---------------- bf16 GEMM (MoE): C[M,N] = A @ BT^T, m97 structure ----------------
// MODE 0: Cf = acc+bias   1: Cb = bf16(acc+bias)
// MODE 3: Cb = bf16( silu(h1)*acc*rowscale[row*4] )  (h1 bf16, may alias Cb)
// MODE 4: Cf += acc
template <int MODE>
__global__ __launch_bounds__(256, 2) void k_gemm(const u16* __restrict__ A, const u16* __restrict__ BT,
                                                 int M, int N, int K, float* __restrict__ Cf,
                                                 u16* __restrict__ Cb, const float* __restrict__ bias,
                                                 const u16* __restrict__ h1,
                                                 const float* __restrict__ rowscale) {
  __shared__ __align__(16) u16 As[4096], Bs[4096];
  const int tid = threadIdx.x, wid = tid >> 6, lane = tid & 63;
  const int l16 = lane & 15, g = lane >> 4;
  const int wr = wid >> 1, wc = wid & 1;
  const int m0 = blockIdx.y * 128, n0 = blockIdx.x * 128;
  const int srow = lane >> 2, scol = (lane & 3) * 8;
  const u16* aS0 = A + (size_t)(m0 + wid * 32 + srow) * K + scol;
  const u16* aS1 = aS0 + (size_t)16 * K;
  const u16* bS0 = BT + (size_t)(n0 + wid * 32 + srow) * K + scol;
  const u16* bS1 = bS0 + (size_t)16 * K;
  u16* aD0 = &As[wid * 1024];
  u16* aD1 = aD0 + 512;
  u16* bD0 = &Bs[wid * 1024];
  u16* bD1 = bD0 + 512;

  const f32x4 zero4 = {0.f, 0.f, 0.f, 0.f};
  f32x4 acc[4][4];
#pragma unroll
  for (int mi = 0; mi < 4; ++mi)
#pragma unroll
    for (int ni = 0; ni < 4; ++ni) acc[mi][ni] = zero4;

  for (int k0 = 0; k0 < K; k0 += 32) {
    __syncthreads();
    gload16(aS0 + k0, aD0);
    gload16(aS1 + k0, aD1);
    gload16(bS0 + k0, bD0);
    gload16(bS1 + k0, bD1);
    __syncthreads();
    bf16x8 af[4], bfr[4];
#pragma unroll
    for (int mi = 0; mi < 4; ++mi)
      af[mi] = *(const bf16x8*)(&As[(wr * 64 + mi * 16 + l16) * 32 + g * 8]);
#pragma unroll
    for (int ni = 0; ni < 4; ++ni)
      bfr[ni] = *(const bf16x8*)(&Bs[(wc * 64 + ni * 16 + l16) * 32 + g * 8]);
#pragma unroll
    for (int mi = 0; mi < 4; ++mi)
#pragma unroll
      for (int ni = 0; ni < 4; ++ni)
        acc[mi][ni] = __builtin_amdgcn_mfma_f32_16x16x32_bf16(af[mi], bfr[ni], acc[mi][ni], 0, 0, 0);
  }

#pragma unroll
  for (int mi = 0; mi < 4; ++mi) {
#pragma unroll
    for (int ni = 0; ni < 4; ++ni) {
      const int col = n0 + wc * 64 + ni * 16 + l16;
      float bv = 0.f;
      if (MODE == 0 || MODE == 1) {
        if (bias) bv = bias[col];
      }
#pragma unroll
      for (int r = 0; r < 4; ++r) {
        const int row = m0 + wr * 64 + mi * 16 + g * 4 + r;
        const size_t idx = (size_t)row * N + col;
        float v = acc[mi][ni][r] + bv;
        if constexpr (MODE == 0) {
          Cf[idx] = v;
        } else if constexpr (MODE == 1) {
          Cb[idx] = f2bf(v);
        } else if constexpr (MODE == 3) {
          float hv = bf2f(h1[idx]);
          float sw = hv * sigf(hv);
          float rs = rowscale ? rowscale[(size_t)row * 4] : 1.f;
          Cb[idx] = f2bf(sw * v * rs);
        } else {
          Cf[idx] += v;
        }
      }
    }
  }
}

// ---------------- split-precision GEMM: A,BT f32; C = A·B^T via 3-term hi/lo bf16 ----------------
// MODE 0: Cf = acc+bias
// MODE 2: Cf = (acc+bias)*gvec[col] + resid
// MODE 6: Cf[col*M+row] = acc+bias   (transposed f32 store, for V^T)
template <int MODE>
__global__ __launch_bounds__(256, 2) void k_gemm3(const float* __restrict__ A, const float* __restrict__ BT,
                                                  int M, int N, int K, float* __restrict__ Cf,
                                                  const float* __restrict__ bias,
                                                  const float* __restrict__ gvec,
                                                  const float* __restrict__ resid) {
  __shared__ __align__(16) float As[4096], Bs[4096];  // [128][32] f32, 16KB each
  const int tid = threadIdx.x, wid = tid >> 6, lane = tid & 63;
  const int l16 = lane & 15, g = lane >> 4;
  const int wr = wid >> 1, wc = wid & 1;
  const int m0 = blockIdx.y * 128, n0 = blockIdx.x * 128;
  const int srow = lane >> 3;        // 0..7 rows per staging call
  const int scol = (lane & 7) * 4;   // f32 col within 32
  const float* aS = A + (size_t)(m0 + wid * 32 + srow) * K + scol;
  const float* bS = BT + (size_t)(n0 + wid * 32 + srow) * K + scol;

  const f32x4 zero4 = {0.f, 0.f, 0.f, 0.f};
  f32x4 acc[4][4];
#pragma unroll
  for (int mi = 0; mi < 4; ++mi)
#pragma unroll
    for (int ni = 0; ni < 4; ++ni) acc[mi][ni] = zero4;

  for (int k0 = 0; k0 < K; k0 += 32) {
    __syncthreads();
#pragma unroll
    for (int c = 0; c < 4; ++c) {
      gload16(aS + (size_t)c * 8 * K + k0, &As[wid * 1024 + c * 256]);
      gload16(bS + (size_t)c * 8 * K + k0, &Bs[wid * 1024 + c * 256]);
    }
    __syncthreads();
    const f32x4* As4 = (const f32x4*)As;
    const f32x4* Bs4 = (const f32x4*)Bs;
    bf16x8 bh[4], bl[4];
#pragma unroll
    for (int ni = 0; ni < 4; ++ni) {
      int rb = wc * 64 + ni * 16 + l16;
      split44(Bs4[rb * 8 + g * 2], Bs4[rb * 8 + g * 2 + 1], bh[ni], bl[ni]);
    }
#pragma unroll
    for (int mi = 0; mi < 4; ++mi) {
      int ra = wr * 64 + mi * 16 + l16;
      bf16x8 ah, al;
      split44(As4[ra * 8 + g * 2], As4[ra * 8 + g * 2 + 1], ah, al);
#pragma unroll
      for (int ni = 0; ni < 4; ++ni) {
        acc[mi][ni] = __builtin_amdgcn_mfma_f32_16x16x32_bf16(al, bh[ni], acc[mi][ni], 0, 0, 0);
        acc[mi][ni] = __builtin_amdgcn_mfma_f32_16x16x32_bf16(ah, bl[ni], acc[mi][ni], 0, 0, 0);
        acc[mi][ni] = __builtin_amdgcn_mfma_f32_16x16x32_bf16(ah, bh[ni], acc[mi][ni], 0, 0, 0);
      }
    }
  }

#pragma unroll
  for (int mi = 0; mi < 4; ++mi) {
#pragma unroll
    for (int ni = 0; ni < 4; ++ni) {
      const int col = n0 + wc * 64 + ni * 16 + l16;
      float bv = bias ? bias[col] : 0.f;
#pragma unroll
      for (int r = 0; r < 4; ++r) {
        const int row = m0 + wr * 64 + mi * 16 + g * 4 + r;
        float v = acc[mi][ni][r] + bv;
        if constexpr (MODE == 0) {
          Cf[(size_t)row * N + col] = v;
        } else if constexpr (MODE == 2) {
          Cf[(size_t)row * N + col] = v * gvec[col] + resid[(size_t)row * N + col];
        } else {
          Cf[(size_t)col * M + row] = v;
        }
      }
    }
  }
}

// ---------------- flash attention, split precision: q,k [S,DIM] f32 (q pre-scaled), vt [DIM,S] f32 ----------------
__global__ __launch_bounds__(256, 2) void k_flash3(const float* __restrict__ q, const float* __restrict__ kk,
                                                   const float* __restrict__ vt, float* __restrict__ o) {
  __shared__ __align__(16) u16 Pah[4][16 * 40], Pal[4][16 * 40];
  const int tid = threadIdx.x, wid = tid >> 6, lane = tid & 63;
  const int l16 = lane & 15, g = lane >> 4;
  const int h = blockIdx.y;
  const int r0 = blockIdx.x * 64 + wid * 16;
  const size_t hOff = (size_t)h * HDIM;

  bf16x8 qh[4], ql[4];
#pragma unroll
  for (int kc = 0; kc < 4; ++kc) {
    const float* qp = q + (size_t)(r0 + l16) * DIMC + hOff + kc * 32 + g * 8;
    split44(*(const f32x4*)qp, *(const f32x4*)(qp + 4), qh[kc], ql[kc]);
  }

  const f32x4 zero4 = {0.f, 0.f, 0.f, 0.f};
  f32x4 oacc[8];
#pragma unroll
  for (int db = 0; db < 8; ++db) oacc[db] = zero4;
  float mr[4], lr[4];
#pragma unroll
  for (int r = 0; r < 4; ++r) {
    mr[r] = -3.0e38f;
    lr[r] = 0.f;
  }

  for (int j0 = 0; j0 < SEQ; j0 += 32) {
    f32x4 s0 = zero4, s1 = zero4;
#pragma unroll
    for (int kc = 0; kc < 4; ++kc) {
      const float* kp0 = kk + (size_t)(j0 + l16) * DIMC + hOff + kc * 32 + g * 8;
      const float* kp1 = kk + (size_t)(j0 + 16 + l16) * DIMC + hOff + kc * 32 + g * 8;
      bf16x8 kh0, kl0, kh1, kl1;
      split44(*(const f32x4*)kp0, *(const f32x4*)(kp0 + 4), kh0, kl0);
      split44(*(const f32x4*)kp1, *(const f32x4*)(kp1 + 4), kh1, kl1);
      s0 = __builtin_amdgcn_mfma_f32_16x16x32_bf16(ql[kc], kh0, s0, 0, 0, 0);
      s0 = __builtin_amdgcn_mfma_f32_16x16x32_bf16(qh[kc], kl0, s0, 0, 0, 0);
      s0 = __builtin_amdgcn_mfma_f32_16x16x32_bf16(qh[kc], kh0, s0, 0, 0, 0);
      s1 = __builtin_amdgcn_mfma_f32_16x16x32_bf16(ql[kc], kh1, s1, 0, 0, 0);
      s1 = __builtin_amdgcn_mfma_f32_16x16x32_bf16(qh[kc], kl1, s1, 0, 0, 0);
      s1 = __builtin_amdgcn_mfma_f32_16x16x32_bf16(qh[kc], kh1, s1, 0, 0, 0);
    }
    float corr[4];
#pragma unroll
    for (int r = 0; r < 4; ++r) {
      float tm = fmaxf(s0[r], s1[r]);
#pragma unroll
      for (int m = 1; m < 16; m <<= 1) tm = fmaxf(tm, __shfl_xor(tm, m));
      float mn = fmaxf(mr[r], tm);
      corr[r] = __expf(mr[r] - mn);
      mr[r] = mn;
      float p0 = __expf(s0[r] - mn);
      float p1 = __expf(s1[r] - mn);
      lr[r] = lr[r] * corr[r] + p0 + p1;
      u16 p0h = f2bf(p0), p1h = f2bf(p1);
      Pah[wid][(g * 4 + r) * 40 + l16] = p0h;
      Pah[wid][(g * 4 + r) * 40 + 16 + l16] = p1h;
      Pal[wid][(g * 4 + r) * 40 + l16] = f2bf(p0 - bf2f(p0h));
      Pal[wid][(g * 4 + r) * 40 + 16 + l16] = f2bf(p1 - bf2f(p1h));
    }
    __syncthreads();
#pragma unroll
    for (int db = 0; db < 8; ++db)
#pragma unroll
      for (int r = 0; r < 4; ++r) oacc[db][r] *= corr[r];
    bf16x8 pfh = *(const bf16x8*)(&Pah[wid][l16 * 40 + g * 8]);
    bf16x8 pfl = *(const bf16x8*)(&Pal[wid][l16 * 40 + g * 8]);
#pragma unroll
    for (int db = 0; db < 8; ++db) {
      const float* vp = vt + (size_t)(hOff + db * 16 + l16) * SEQ + j0 + g * 8;
      bf16x8 vh, vl;
      split44(*(const f32x4*)vp, *(const f32x4*)(vp + 4), vh, vl);
      oacc[db] = __builtin_amdgcn_mfma_f32_16x16x32_bf16(pfl, vh, oacc[db], 0, 0, 0);
      oacc[db] = __builtin_amdgcn_mfma_f32_16x16x32_bf16(pfh, vl, oacc[db], 0, 0, 0);
      oacc[db] = __builtin_amdgcn_mfma_f32_16x16x32_bf16(pfh, vh, oacc[db], 0, 0, 0);
    }
  }
#pragma unroll
  for (int r = 0; r < 4; ++r) {
#pragma unroll
    for (int m = 1; m < 16; m <<= 1) lr[r] += __shfl_xor(lr[r], m);
    lr[r] = 1.f / lr[r];
  }
#pragma unroll
  for (int db = 0; db < 8; ++db)
#pragma unroll
    for (int r = 0; r < 4; ++r)
      o[(size_t)(r0 + g * 4 + r) * DIMC + hOff + db * 16 + l16] = oacc[db][r] * lr[r];
}

// ---------------- final: out = g_mlp[col]*ff + img   (img aliases out; in-place) ----------------
__global__ __launch_bounds__(256) void k_final(const float* __restrict__ ff, const float* img,
                                               const float* __restrict__ mod, float* out) {
  const float4* gm = (const float4*)(mod + 5 * DIMC);
  const int total = SEQ * DIMC / 4;
  const int stride = gridDim.x * blockDim.x;
  for (int i = blockIdx.x * blockDim.x + threadIdx.x; i < total; i += stride) {
    int col4 = i & (DIMC / 4 - 1);
    float4 gv = gm[col4];
    float4 fv = ((const float4*)ff)[i];
    float4 iv = ((const float4*)img)[i];
    float4 ov;
    ov.x = gv.x * fv.x + iv.x;
    ov.y = gv.y * fv.y + iv.y;
    ov.z = gv.z * fv.z + iv.z;
    ov.w = gv.w * fv.w + iv.w;
    ((float4*)out)[i] = ov;
  }
}

extern "C" void kernel_launch(void* const* d_in, const int* in_sizes, int n_in, void* d_out, int out_size,
                              void* d_ws, size_t ws_size, hipStream_t stream) {
  (void)in_sizes; (void)n_in; (void)out_size; (void)ws_size;
  const float* image_tokens = (const float*)d_in[0];
  const float* adaln_input = (const float*)d_in[1];
  const float* W_ada = (const float*)d_in[2];
  const float* b_ada = (const float*)d_in[3];
  const float* Wq = (const float*)d_in[4];
  const float* bq = (const float*)d_in[5];
  const float* Wk = (const float*)d_in[6];
  const float* bk = (const float*)d_in[7];
  const float* Wv = (const float*)d_in[8];
  const float* bv = (const float*)d_in[9];
  const float* q_rms_w = (const float*)d_in[10];
  const float* k_rms_w = (const float*)d_in[11];
  const float* Wo = (const float*)d_in[12];
  const float* bo = (const float*)d_in[13];
  const float* gate_w = (const float*)d_in[14];
  const float* We1 = (const float*)d_in[15];
  const float* We3 = (const float*)d_in[16];
  const float* We2 = (const float*)d_in[17];
  const float* Ws1 = (const float*)d_in[18];
  const float* Ws3 = (const float*)d_in[19];
  const float* Ws2 = (const float*)d_in[20];

  // ---- workspace: ~166 MB, no aliasing (R1 ran a ~302 MB arena sanely -> ws >= ~300 MB) ----
  char* cur = (char*)d_ws;
  auto alloc = [&](size_t n) {
    char* p = cur;
    cur += (n + 255) & ~(size_t)255;
    return p;
  };
  float* modv = (float*)alloc((size_t)MOD6 * 4);
  float* adap = (float*)alloc((size_t)16 * MOD6 * 4);
  float* comb = (float*)alloc((size_t)SEQ * NEXP * 4);
  float* xf = (float*)alloc((size_t)SEQ * DIMC * 4);    // f32 modulated x (attention)
  float* wTf = (float*)alloc((size_t)DIMC * DIMC * 4);  // f32 transposed attention weight
  float* tf = (float*)alloc((size_t)SEQ * DIMC * 4);    // f32 q_raw / k_raw scratch
  float* qf = (float*)alloc((size_t)SEQ * DIMC * 4);    // f32 q (rms'd, scaled)
  float* kf = (float*)alloc((size_t)SEQ * DIMC * 4);    // f32 k (rms'd)
  float* vtf = (float*)alloc((size_t)SEQ * DIMC * 4);   // f32 V^T
  float* aof = (float*)alloc((size_t)SEQ * DIMC * 4);   // f32 attention out
  u16* x_act = (u16*)alloc((size_t)SEQ * DIMC * 2);     // bf16 MoE input
  u16* wbuf = (u16*)alloc((size_t)HSH * DIMC * 2);      // bf16 MoE transpose buffer
  u16* H1G = (u16*)alloc((size_t)SEQ * HSH * 2);        // bf16 H1 -> G (in place)
  float* ff = (float*)alloc((size_t)SEQ * DIMC * 4);    // f32 FFN accumulator
  float* img = (float*)d_out;                           // written by MODE2 before any read

  dim3 blk(256);
  auto gemm3 = [&](int mode, const float* A, const float* BT, int M, int N, int K, float* Cf,
                   const float* bias, const float* gv, const float* resid) {
    dim3 grid(N / 128, M / 128);
    switch (mode) {
      case 0: k_gemm3<0><<<grid, blk, 0, stream>>>(A, BT, M, N, K, Cf, bias, gv, resid); break;
      case 2: k_gemm3<2><<<grid, blk, 0, stream>>>(A, BT, M, N, K, Cf, bias, gv, resid); break;
      default: k_gemm3<6><<<grid, blk, 0, stream>>>(A, BT, M, N, K, Cf, bias, gv, resid); break;
    }
  };
  auto gemm = [&](int mode, const u16* A, const u16* BT, int M, int N, int K, float* Cf, u16* Cb,
                  const float* bias, const u16* h1, const float* rs) {
    dim3 grid(N / 128, M / 128);
    switch (mode) {
      case 0: k_gemm<0><<<grid, blk, 0, stream>>>(A, BT, M, N, K, Cf, Cb, bias, h1, rs); break;
      case 1: k_gemm<1><<<grid, blk, 0, stream>>>(A, BT, M, N, K, Cf, Cb, bias, h1, rs); break;
      case 3: k_gemm<3><<<grid, blk, 0, stream>>>(A, BT, M, N, K, Cf, Cb, bias, h1, rs); break;
      default: k_gemm<4><<<grid, blk, 0, stream>>>(A, BT, M, N, K, Cf, Cb, bias, h1, rs); break;
    }
  };

  // adaLN modulation vector
  k_adaln_p<<<dim3(MOD6 / 256, 16), blk, 0, stream>>>(adaln_input, W_ada, adap);
  k_adaln_r<<<dim3(MOD6 / 256), blk, 0, stream>>>(adap, b_ada, modv);

  // ---- attention branch (f32-accurate via split-bf16 GEMMs) ----
  k_ln_modf<<<dim3(SEQ), blk, 0, stream>>>(image_tokens, modv, 0, DIMC, xf);
  k_transpose_f<<<dim3(DIMC / 32, DIMC / 32), blk, 0, stream>>>(Wq, wTf, DIMC, DIMC, DIMC);
  gemm3(0, xf, wTf, SEQ, DIMC, DIMC, tf, bq, nullptr, nullptr);
  k_rms_f32<<<dim3(SEQ), blk, 0, stream>>>(tf, q_rms_w, 0.08838834764831845f, qf);
  k_transpose_f<<<dim3(DIMC / 32, DIMC / 32), blk, 0, stream>>>(Wk, wTf, DIMC, DIMC, DIMC);
  gemm3(0, xf, wTf, SEQ, DIMC, DIMC, tf, bk, nullptr, nullptr);
  k_rms_f32<<<dim3(SEQ), blk, 0, stream>>>(tf, k_rms_w, 1.f, kf);
  k_transpose_f<<<dim3(DIMC / 32, DIMC / 32), blk, 0, stream>>>(Wv, wTf, DIMC, DIMC, DIMC);
  gemm3(6, xf, wTf, SEQ, DIMC, DIMC, vtf, bv, nullptr, nullptr);
  k_flash3<<<dim3(SEQ / 64, NHEAD), blk, 0, stream>>>(qf, kf, vtf, aof);
  k_transpose_f<<<dim3(DIMC / 32, DIMC / 32), blk, 0, stream>>>(Wo, wTf, DIMC, DIMC, DIMC);
  gemm3(2, aof, wTf, SEQ, DIMC, DIMC, img, bo, modv + 2 * DIMC, image_tokens);

  // ---- MoE branch (bf16; selection decided in f32 by k_gate) ----
  k_ln_mod<<<dim3(SEQ), blk, 0, stream>>>(img, modv, 3 * DIMC, 4 * DIMC, x_act);
  k_gate<<<dim3(SEQ), blk, 0, stream>>>(img, modv, gate_w, comb);
  bool first = true;
  for (int e = 0; e < NEXP; ++e) {
    for (int h = 0; h < 2; ++h) {
      const float* We1h = We1 + (size_t)e * DIMC * HIDC + (size_t)h * HSH;
      const float* We3h = We3 + (size_t)e * DIMC * HIDC + (size_t)h * HSH;
      const float* We2h = We2 + (size_t)e * HIDC * DIMC + (size_t)h * HSH * DIMC;
      k_transpose<<<dim3(HSH / 32, DIMC / 32), blk, 0, stream>>>(We1h, wbuf, DIMC, HSH, HIDC);
      gemm(1, x_act, wbuf, SEQ, HSH, DIMC, nullptr, H1G, nullptr, nullptr, nullptr);
      k_transpose<<<dim3(HSH / 32, DIMC / 32), blk, 0, stream>>>(We3h, wbuf, DIMC, HSH, HIDC);
      gemm(3, x_act, wbuf, SEQ, HSH, DIMC, nullptr, H1G, nullptr, H1G, comb + e);
      k_transpose<<<dim3(DIMC / 32, HSH / 32), blk, 0, stream>>>(We2h, wbuf, HSH, DIMC, DIMC);
      gemm(first ? 0 : 4, H1G, wbuf, SEQ, DIMC, HSH, ff, nullptr, nullptr, nullptr, nullptr);
      first = false;
    }
  }
  // shared expert
  k_transpose<<<dim3(HSH / 32, DIMC / 32), blk, 0, stream>>>(Ws1, wbuf, DIMC, HSH, HSH);
  gemm(1, x_act, wbuf, SEQ, HSH, DIMC, nullptr, H1G, nullptr, nullptr, nullptr);
  k_transpose<<<dim3(HSH / 32, DIMC / 32), blk, 0, stream>>>(Ws3, wbuf, DIMC, HSH, HSH);
  gemm(3, x_act, wbuf, SEQ, HSH, DIMC, nullptr, H1G, nullptr, H1G, nullptr);
  k_transpose<<<dim3(DIMC / 32, HSH / 32), blk, 0, stream>>>(Ws2, wbuf, HSH, DIMC, DIMC);
  gemm(4, H1G, wbuf, SEQ, DIMC, HSH, ff, nullptr, nullptr, nullptr, nullptr);

  k_final<<<dim3(1024), blk, 0, stream>>>(ff, img, modv, (float*)d_out);
}

// Round 5
// 2419.088 us; speedup vs baseline: 1.1687x; 1.1687x over previous
//
#include <hip/hip_runtime.h>
#include <hip/hip_bf16.h>

typedef unsigned short u16;
typedef __bf16 bf16x8 __attribute__((ext_vector_type(8)));
typedef float f32x4 __attribute__((ext_vector_type(4)));
typedef unsigned short u16x8 __attribute__((ext_vector_type(8)));

constexpr int DIMC = 2048;
constexpr int SEQ = 2048;
constexpr int NHEAD = 16;
constexpr int HDIM = 128;
constexpr int NEXP = 4;
constexpr int HIDC = 5632;
constexpr int HSH = 2816;  // == HIDC/2
constexpr int MOD6 = 6 * DIMC;

static __device__ __forceinline__ u16 f2bf(float f) {
  __hip_bfloat16 b = __float2bfloat16(f);
  return __builtin_bit_cast(u16, b);
}
static __device__ __forceinline__ float bf2f(u16 u) {
  unsigned int x = ((unsigned int)u) << 16;
  return __builtin_bit_cast(float, x);
}
static __device__ __forceinline__ float sigf(float x) { return 1.f / (1.f + __expf(-x)); }

static __device__ __forceinline__ void gload16(const void* src, void* dst) {
  __builtin_amdgcn_global_load_lds((const __attribute__((address_space(1))) void*)src,
                                   (__attribute__((address_space(3))) void*)dst, 16, 0, 0);
}

// split f32 8-vector (two f32x4) into hi/lo bf16x8: v ≈ h + l
static __device__ __forceinline__ void split44(f32x4 lo, f32x4 hi, bf16x8& h, bf16x8& l) {
#pragma unroll
  for (int e = 0; e < 4; ++e) {
    float f0 = lo[e];
    u16 h0 = f2bf(f0);
    h[e] = __builtin_bit_cast(__bf16, h0);
    l[e] = __builtin_bit_cast(__bf16, f2bf(f0 - bf2f(h0)));
    float f1 = hi[e];
    u16 h1 = f2bf(f1);
    h[4 + e] = __builtin_bit_cast(__bf16, h1);
    l[4 + e] = __builtin_bit_cast(__bf16, f2bf(f1 - bf2f(h1)));
  }
}

// block = 256 threads (4 waves); returns total across block to all threads
static __device__ __forceinline__ float blockSum(float v) {
#pragma unroll
  for (int m = 1; m < 64; m <<= 1) v += __shfl_xor(v, m);
  __shared__ float s[4];
  int w = threadIdx.x >> 6;
  if ((threadIdx.x & 63) == 0) s[w] = v;
  __syncthreads();
  float r = s[0] + s[1] + s[2] + s[3];
  __syncthreads();
  return r;
}

// ---------------- transpose f32 [R,C] (row stride ldin) -> bf16 [C,R] ----------------
__global__ __launch_bounds__(256) void k_transpose(const float* __restrict__ in, u16* __restrict__ out,
                                                   int R, int C, int ldin) {
  __shared__ __align__(16) float tile[32][33];
  int tx = threadIdx.x & 31, ty = threadIdx.x >> 5;
  int c0 = blockIdx.x * 32, r0 = blockIdx.y * 32;
#pragma unroll
  for (int i = 0; i < 32; i += 8)
    tile[ty + i][tx] = in[(size_t)(r0 + ty + i) * ldin + c0 + tx];
  __syncthreads();
#pragma unroll
  for (int i = 0; i < 32; i += 8)
    out[(size_t)(c0 + ty + i) * R + r0 + tx] = f2bf(tile[tx][ty + i]);
}

// ---------------- transpose f32 [R,C] -> f32 [C,R] (attention weights) ----------------
__global__ __launch_bounds__(256) void k_transpose_f(const float* __restrict__ in, float* __restrict__ out,
                                                     int R, int C, int ldin) {
  __shared__ __align__(16) float tile[32][33];
  int tx = threadIdx.x & 31, ty = threadIdx.x >> 5;
  int c0 = blockIdx.x * 32, r0 = blockIdx.y * 32;
#pragma unroll
  for (int i = 0; i < 32; i += 8)
    tile[ty + i][tx] = in[(size_t)(r0 + ty + i) * ldin + c0 + tx];
  __syncthreads();
#pragma unroll
  for (int i = 0; i < 32; i += 8)
    out[(size_t)(c0 + ty + i) * R + r0 + tx] = tile[tx][ty + i];
}

// ---------------- adaLN: mod = silu(a) @ W_ada + b_ada, split over 16 d-slices ----------------
__global__ __launch_bounds__(256) void k_adaln_p(const float* __restrict__ a, const float* __restrict__ W,
                                                 float* __restrict__ partial) {
  __shared__ float sa[128];
  int tid = threadIdx.x, slice = blockIdx.y;
  if (tid < 128) { float v = a[slice * 128 + tid]; sa[tid] = v * sigf(v); }
  __syncthreads();
  int j = blockIdx.x * 256 + tid;
  float acc = 0.f;
#pragma unroll 4
  for (int d = 0; d < 128; ++d) acc += sa[d] * W[(size_t)(slice * 128 + d) * MOD6 + j];
  partial[(size_t)slice * MOD6 + j] = acc;
}
__global__ __launch_bounds__(256) void k_adaln_r(const float* __restrict__ partial, const float* __restrict__ b,
                                                 float* __restrict__ mod) {
  int j = blockIdx.x * 256 + threadIdx.x;
  float acc = b[j];
#pragma unroll
  for (int s = 0; s < 16; ++s) acc += partial[(size_t)s * MOD6 + j];
  mod[j] = acc;
}

// ---------------- LayerNorm + adaLN modulate -> f32 (attention x) ----------------
__global__ __launch_bounds__(256) void k_ln_modf(const float* __restrict__ X, const float* __restrict__ mod,
                                                 int shOff, int scOff, float* __restrict__ out) {
  int row = blockIdx.x, tid = threadIdx.x;
  const float4* x4 = (const float4*)(X + (size_t)row * DIMC);
  float4 v0 = x4[tid * 2], v1 = x4[tid * 2 + 1];
  float s = v0.x + v0.y + v0.z + v0.w + v1.x + v1.y + v1.z + v1.w;
  float ss = v0.x * v0.x + v0.y * v0.y + v0.z * v0.z + v0.w * v0.w +
             v1.x * v1.x + v1.y * v1.y + v1.z * v1.z + v1.w * v1.w;
  s = blockSum(s);
  ss = blockSum(ss);
  float mean = s * (1.f / DIMC);
  float var = ss * (1.f / DIMC) - mean * mean;
  float rstd = rsqrtf(var + 1e-6f);
  const float* sh = mod + shOff;
  const float* sc = mod + scOff;
  int c = tid * 8;
  float xv[8] = {v0.x, v0.y, v0.z, v0.w, v1.x, v1.y, v1.z, v1.w};
  float4 o0, o1;
  float ov[8];
#pragma unroll
  for (int e = 0; e < 8; ++e) ov[e] = (xv[e] - mean) * rstd * (1.f + sc[c + e]) + sh[c + e];
  o0.x = ov[0]; o0.y = ov[1]; o0.z = ov[2]; o0.w = ov[3];
  o1.x = ov[4]; o1.y = ov[5]; o1.z = ov[6]; o1.w = ov[7];
  float4* y4 = (float4*)(out + (size_t)row * DIMC);
  y4[tid * 2] = o0;
  y4[tid * 2 + 1] = o1;
}

// ---------------- LayerNorm + adaLN modulate -> bf16 (MoE x_act) ----------------
__global__ __launch_bounds__(256) void k_ln_mod(const float* __restrict__ X, const float* __restrict__ mod,
                                                int shOff, int scOff, u16* __restrict__ out) {
  int row = blockIdx.x, tid = threadIdx.x;
  const float4* x4 = (const float4*)(X + (size_t)row * DIMC);
  float4 v0 = x4[tid * 2], v1 = x4[tid * 2 + 1];
  float s = v0.x + v0.y + v0.z + v0.w + v1.x + v1.y + v1.z + v1.w;
  float ss = v0.x * v0.x + v0.y * v0.y + v0.z * v0.z + v0.w * v0.w +
             v1.x * v1.x + v1.y * v1.y + v1.z * v1.z + v1.w * v1.w;
  s = blockSum(s);
  ss = blockSum(ss);
  float mean = s * (1.f / DIMC);
  float var = ss * (1.f / DIMC) - mean * mean;
  float rstd = rsqrtf(var + 1e-6f);
  const float* sh = mod + shOff;
  const float* sc = mod + scOff;
  int c = tid * 8;
  float xv[8] = {v0.x, v0.y, v0.z, v0.w, v1.x, v1.y, v1.z, v1.w};
  u16x8 o;
#pragma unroll
  for (int e = 0; e < 8; ++e) o[e] = f2bf((xv[e] - mean) * rstd * (1.f + sc[c + e]) + sh[c + e]);
  *(u16x8*)(out + (size_t)row * DIMC + c) = o;
}

// ---------------- RMSNorm f32 in -> f32 out, * weight * scale ----------------
__global__ __launch_bounds__(256) void k_rms_f32(const float* __restrict__ X, const float* __restrict__ w,
                                                 float scale, float* __restrict__ out) {
  int row = blockIdx.x, tid = threadIdx.x;
  const float4* x4 = (const float4*)(X + (size_t)row * DIMC);
  float4 v0 = x4[tid * 2], v1 = x4[tid * 2 + 1];
  float ss = v0.x * v0.x + v0.y * v0.y + v0.z * v0.z + v0.w * v0.w +
             v1.x * v1.x + v1.y * v1.y + v1.z * v1.z + v1.w * v1.w;
  ss = blockSum(ss);
  float rstd = rsqrtf(ss * (1.f / DIMC) + 1e-5f) * scale;
  int c = tid * 8;
  float xv[8] = {v0.x, v0.y, v0.z, v0.w, v1.x, v1.y, v1.z, v1.w};
  float ov[8];
#pragma unroll
  for (int e = 0; e < 8; ++e) ov[e] = xv[e] * rstd * w[c + e];
  float4 o0 = {ov[0], ov[1], ov[2], ov[3]}, o1 = {ov[4], ov[5], ov[6], ov[7]};
  float4* y4 = (float4*)(out + (size_t)row * DIMC);
  y4[tid * 2] = o0;
  y4[tid * 2 + 1] = o1;
}

// ---------------- gating: recompute LN+mod in f32, softmax over 4, top-2 -> comb[n][4] ----------------
__global__ __launch_bounds__(256) void k_gate(const float* __restrict__ img, const float* __restrict__ mod,
                                              const float* __restrict__ gw, float* __restrict__ comb) {
  int n = blockIdx.x, tid = threadIdx.x;
  const float4* x4 = (const float4*)(img + (size_t)n * DIMC);
  float4 v0 = x4[tid * 2], v1 = x4[tid * 2 + 1];
  float s = v0.x + v0.y + v0.z + v0.w + v1.x + v1.y + v1.z + v1.w;
  float ss = v0.x * v0.x + v0.y * v0.y + v0.z * v0.z + v0.w * v0.w +
             v1.x * v1.x + v1.y * v1.y + v1.z * v1.z + v1.w * v1.w;
  s = blockSum(s);
  ss = blockSum(ss);
  float mean = s * (1.f / DIMC);
  float var = ss * (1.f / DIMC) - mean * mean;
  float rstd = rsqrtf(var + 1e-6f);
  const float* sh = mod + 3 * DIMC;
  const float* sc = mod + 4 * DIMC;
  int c = tid * 8;
  float xv[8] = {v0.x, v0.y, v0.z, v0.w, v1.x, v1.y, v1.z, v1.w};
  float y[8];
#pragma unroll
  for (int e = 0; e < 8; ++e) y[e] = (xv[e] - mean) * rstd * (1.f + sc[c + e]) + sh[c + e];
  float accs[NEXP];
#pragma unroll
  for (int ex = 0; ex < NEXP; ++ex) {
    float a = 0.f;
#pragma unroll
    for (int e = 0; e < 8; ++e) a += y[e] * gw[(size_t)ex * DIMC + c + e];
    accs[ex] = blockSum(a);
  }
  if (tid == 0) {
    float mx = fmaxf(fmaxf(accs[0], accs[1]), fmaxf(accs[2], accs[3]));
    float ex0 = __expf(accs[0] - mx), ex1 = __expf(accs[1] - mx);
    float ex2 = __expf(accs[2] - mx), ex3 = __expf(accs[3] - mx);
    float inv = 1.f / (ex0 + ex1 + ex2 + ex3);
    float v[4] = {ex0 * inv, ex1 * inv, ex2 * inv, ex3 * inv};
    int i1 = 0;
    for (int e = 1; e < 4; ++e)
      if (v[e] > v[i1]) i1 = e;
    int i2 = -1;
    for (int e = 0; e < 4; ++e) {
      if (e == i1) continue;
      if (i2 < 0 || v[e] > v[i2]) i2 = e;
    }
    for (int e = 0; e < 4; ++e) comb[(size_t)n * 4 + e] = (e == i1 || e == i2) ? v[e] : 0.f;
  }
}

// ---------------- bf16 GEMM (MoE): C[M,N] = A @ BT^T, m97 structure (UNCHANGED, verified) ----------------
// MODE 0: Cf = acc+bias   1: Cb = bf16(acc+bias)
// MODE 3: Cb = bf16( silu(h1)*acc*rowscale[row*4] )  (h1 bf16, may alias Cb)
// MODE 4: Cf += acc
template <int MODE>
__global__ __launch_bounds__(256, 2) void k_gemm(const u16* __restrict__ A, const u16* __restrict__ BT,
                                                 int M, int N, int K, float* __restrict__ Cf,
                                                 u16* __restrict__ Cb, const float* __restrict__ bias,
                                                 const u16* __restrict__ h1,
                                                 const float* __restrict__ rowscale) {
  __shared__ __align__(16) u16 As[4096], Bs[4096];
  const int tid = threadIdx.x, wid = tid >> 6, lane = tid & 63;
  const int l16 = lane & 15, g = lane >> 4;
  const int wr = wid >> 1, wc = wid & 1;
  const int m0 = blockIdx.y * 128, n0 = blockIdx.x * 128;
  const int srow = lane >> 2, scol = (lane & 3) * 8;
  const u16* aS0 = A + (size_t)(m0 + wid * 32 + srow) * K + scol;
  const u16* aS1 = aS0 + (size_t)16 * K;
  const u16* bS0 = BT + (size_t)(n0 + wid * 32 + srow) * K + scol;
  const u16* bS1 = bS0 + (size_t)16 * K;
  u16* aD0 = &As[wid * 1024];
  u16* aD1 = aD0 + 512;
  u16* bD0 = &Bs[wid * 1024];
  u16* bD1 = bD0 + 512;

  const f32x4 zero4 = {0.f, 0.f, 0.f, 0.f};
  f32x4 acc[4][4];
#pragma unroll
  for (int mi = 0; mi < 4; ++mi)
#pragma unroll
    for (int ni = 0; ni < 4; ++ni) acc[mi][ni] = zero4;

  for (int k0 = 0; k0 < K; k0 += 32) {
    __syncthreads();
    gload16(aS0 + k0, aD0);
    gload16(aS1 + k0, aD1);
    gload16(bS0 + k0, bD0);
    gload16(bS1 + k0, bD1);
    __syncthreads();
    bf16x8 af[4], bfr[4];
#pragma unroll
    for (int mi = 0; mi < 4; ++mi)
      af[mi] = *(const bf16x8*)(&As[(wr * 64 + mi * 16 + l16) * 32 + g * 8]);
#pragma unroll
    for (int ni = 0; ni < 4; ++ni)
      bfr[ni] = *(const bf16x8*)(&Bs[(wc * 64 + ni * 16 + l16) * 32 + g * 8]);
#pragma unroll
    for (int mi = 0; mi < 4; ++mi)
#pragma unroll
      for (int ni = 0; ni < 4; ++ni)
        acc[mi][ni] = __builtin_amdgcn_mfma_f32_16x16x32_bf16(af[mi], bfr[ni], acc[mi][ni], 0, 0, 0);
  }

#pragma unroll
  for (int mi = 0; mi < 4; ++mi) {
#pragma unroll
    for (int ni = 0; ni < 4; ++ni) {
      const int col = n0 + wc * 64 + ni * 16 + l16;
      float bv = 0.f;
      if (MODE == 0 || MODE == 1) {
        if (bias) bv = bias[col];
      }
#pragma unroll
      for (int r = 0; r < 4; ++r) {
        const int row = m0 + wr * 64 + mi * 16 + g * 4 + r;
        const size_t idx = (size_t)row * N + col;
        float v = acc[mi][ni][r] + bv;
        if constexpr (MODE == 0) {
          Cf[idx] = v;
        } else if constexpr (MODE == 1) {
          Cb[idx] = f2bf(v);
        } else if constexpr (MODE == 3) {
          float hv = bf2f(h1[idx]);
          float sw = hv * sigf(hv);
          float rs = rowscale ? rowscale[(size_t)row * 4] : 1.f;
          Cb[idx] = f2bf(sw * v * rs);
        } else {
          Cf[idx] += v;
        }
      }
    }
  }
}

// ---------------- split-precision GEMM v2: reg-stage + pre-split hi/lo LDS ----------------
// MODE 0: Cf = acc+bias
// MODE 2: Cf = (acc+bias)*gvec[col] + resid
// MODE 6: Cf[col*M+row] = acc+bias   (transposed f32 store, for V^T)
template <int MODE>
__global__ __launch_bounds__(256, 2) void k_gemm3(const float* __restrict__ A, const float* __restrict__ BT,
                                                  int M, int N, int K, float* __restrict__ Cf,
                                                  const float* __restrict__ bias,
                                                  const float* __restrict__ gvec,
                                                  const float* __restrict__ resid) {
  // [128][32] u16 each, byte-swizzled: data(row,e) at byte row*64 + ((e*2) ^ ((row&3)<<4))
  __shared__ __align__(16) u16 Ah[4096], Al[4096], Bh[4096], Bl[4096];
  const int tid = threadIdx.x, wid = tid >> 6, lane = tid & 63;
  const int l16 = lane & 15, g = lane >> 4;
  const int wr = wid >> 1, wc = wid & 1;
  const int m0 = blockIdx.y * 128, n0 = blockIdx.x * 128;

  // staging geometry: thread -> row (0..127), 16-element chunk (0/16)
  const int srow = tid >> 1, se0 = (tid & 1) * 16;
  const int sswz = (srow & 3) << 4;
  const int c0 = (se0 * 2) ^ sswz, c1 = (se0 * 2 + 16) ^ sswz;
  char* ahp = (char*)Ah + srow * 64;
  char* alp = (char*)Al + srow * 64;
  char* bhp = (char*)Bh + srow * 64;
  char* blp = (char*)Bl + srow * 64;
  const float* aS = A + (size_t)(m0 + srow) * K + se0;
  const float* bS = BT + (size_t)(n0 + srow) * K + se0;

  f32x4 ar[4], br[4];
#pragma unroll
  for (int c = 0; c < 4; ++c) {
    ar[c] = *(const f32x4*)(aS + c * 4);
    br[c] = *(const f32x4*)(bS + c * 4);
  }

  const f32x4 zero4 = {0.f, 0.f, 0.f, 0.f};
  f32x4 acc[4][4];
#pragma unroll
  for (int mi = 0; mi < 4; ++mi)
#pragma unroll
    for (int ni = 0; ni < 4; ++ni) acc[mi][ni] = zero4;

  for (int k0 = 0; k0 < K; k0 += 32) {
    __syncthreads();  // prior iteration's LDS frag reads done
    bf16x8 h0, l0, h1, l1;
    split44(ar[0], ar[1], h0, l0);
    split44(ar[2], ar[3], h1, l1);
    *(bf16x8*)(ahp + c0) = h0;
    *(bf16x8*)(ahp + c1) = h1;
    *(bf16x8*)(alp + c0) = l0;
    *(bf16x8*)(alp + c1) = l1;
    split44(br[0], br[1], h0, l0);
    split44(br[2], br[3], h1, l1);
    *(bf16x8*)(bhp + c0) = h0;
    *(bf16x8*)(bhp + c1) = h1;
    *(bf16x8*)(blp + c0) = l0;
    *(bf16x8*)(blp + c1) = l1;
    __syncthreads();  // staged tile visible
    if (k0 + 32 < K) {  // T14: issue next tile's loads; MFMAs below hide the latency
#pragma unroll
      for (int c = 0; c < 4; ++c) {
        ar[c] = *(const f32x4*)(aS + k0 + 32 + c * 4);
        br[c] = *(const f32x4*)(bS + k0 + 32 + c * 4);
      }
    }
    bf16x8 bhf[4], blf[4];
#pragma unroll
    for (int ni = 0; ni < 4; ++ni) {
      const int rb = wc * 64 + ni * 16 + l16;
      const int cb = (g * 16) ^ ((rb & 3) << 4);
      bhf[ni] = *(const bf16x8*)((char*)Bh + rb * 64 + cb);
      blf[ni] = *(const bf16x8*)((char*)Bl + rb * 64 + cb);
    }
#pragma unroll
    for (int mi = 0; mi < 4; ++mi) {
      const int ra = wr * 64 + mi * 16 + l16;
      const int ca = (g * 16) ^ ((ra & 3) << 4);
      bf16x8 ahf = *(const bf16x8*)((char*)Ah + ra * 64 + ca);
      bf16x8 alf = *(const bf16x8*)((char*)Al + ra * 64 + ca);
#pragma unroll
      for (int ni = 0; ni < 4; ++ni) {
        acc[mi][ni] = __builtin_amdgcn_mfma_f32_16x16x32_bf16(alf, bhf[ni], acc[mi][ni], 0, 0, 0);
        acc[mi][ni] = __builtin_amdgcn_mfma_f32_16x16x32_bf16(ahf, blf[ni], acc[mi][ni], 0, 0, 0);
        acc[mi][ni] = __builtin_amdgcn_mfma_f32_16x16x32_bf16(ahf, bhf[ni], acc[mi][ni], 0, 0, 0);
      }
    }
  }

#pragma unroll
  for (int mi = 0; mi < 4; ++mi) {
#pragma unroll
    for (int ni = 0; ni < 4; ++ni) {
      const int col = n0 + wc * 64 + ni * 16 + l16;
      float bv = bias ? bias[col] : 0.f;
#pragma unroll
      for (int r = 0; r < 4; ++r) {
        const int row = m0 + wr * 64 + mi * 16 + g * 4 + r;
        float v = acc[mi][ni][r] + bv;
        if constexpr (MODE == 0) {
          Cf[(size_t)row * N + col] = v;
        } else if constexpr (MODE == 2) {
          Cf[(size_t)row * N + col] = v * gvec[col] + resid[(size_t)row * N + col];
        } else {
          Cf[(size_t)col * M + row] = v;
        }
      }
    }
  }
}

// ---------------- flash attention v2: block-staged pre-split K/V in LDS ----------------
// q,k [S,DIM] f32 (q pre-scaled), vt [DIM,S] f32
__global__ __launch_bounds__(256, 2) void k_flash3(const float* __restrict__ q, const float* __restrict__ kk,
                                                   const float* __restrict__ vt, float* __restrict__ o) {
  // K tiles [32][128] u16: data(r,d) at byte r*256 + ((d*2) ^ ((r&7)<<4))
  // V^T tiles [128][32] u16: data(d,j) at byte d*64 + ((j*2) ^ ((d&3)<<4))
  __shared__ __align__(16) u16 Kh[4096], Kl[4096], Vh[4096], Vl[4096];
  __shared__ __align__(16) u16 Pah[4][16 * 40], Pal[4][16 * 40];
  const int tid = threadIdx.x, wid = tid >> 6, lane = tid & 63;
  const int l16 = lane & 15, g = lane >> 4;
  const int h = blockIdx.y;
  const int r0 = blockIdx.x * 64 + wid * 16;
  const size_t hOff = (size_t)h * HDIM;

  bf16x8 qh[4], ql[4];
#pragma unroll
  for (int kc = 0; kc < 4; ++kc) {
    const float* qp = q + (size_t)(r0 + l16) * DIMC + hOff + kc * 32 + g * 8;
    split44(*(const f32x4*)qp, *(const f32x4*)(qp + 4), qh[kc], ql[kc]);
  }

  // staging geometry
  const int kr = tid >> 3, ke0 = (tid & 7) * 16;  // K: row 0..31, 16-elem chunk
  const int kswz = (kr & 7) << 4;
  const int kc0 = (ke0 * 2) ^ kswz, kc1 = (ke0 * 2 + 16) ^ kswz;
  char* khp = (char*)Kh + kr * 256;
  char* klp = (char*)Kl + kr * 256;
  const float* kBase = kk + (size_t)kr * DIMC + hOff + ke0;  // + j0*DIMC per tile
  const int vr = tid >> 1, ve0 = (tid & 1) * 16;  // V: row(d) 0..127, 16-elem chunk
  const int vswz = (vr & 3) << 4;
  const int vc0 = (ve0 * 2) ^ vswz, vc1 = (ve0 * 2 + 16) ^ vswz;
  char* vhp = (char*)Vh + vr * 64;
  char* vlp = (char*)Vl + vr * 64;
  const float* vBase = vt + (size_t)(hOff + vr) * SEQ + ve0;  // + j0 per tile

  f32x4 kReg[4], vReg[4];
#pragma unroll
  for (int c = 0; c < 4; ++c) {
    kReg[c] = *(const f32x4*)(kBase + c * 4);
    vReg[c] = *(const f32x4*)(vBase + c * 4);
  }

  const f32x4 zero4 = {0.f, 0.f, 0.f, 0.f};
  f32x4 oacc[8];
#pragma unroll
  for (int db = 0; db < 8; ++db) oacc[db] = zero4;
  float mr[4], lr[4];
#pragma unroll
  for (int r = 0; r < 4; ++r) {
    mr[r] = -3.0e38f;
    lr[r] = 0.f;
  }

  for (int j0 = 0; j0 < SEQ; j0 += 32) {
    __syncthreads();  // all waves done reading prior K/V tiles
    bf16x8 h0, l0, h1, l1;
    split44(kReg[0], kReg[1], h0, l0);
    split44(kReg[2], kReg[3], h1, l1);
    *(bf16x8*)(khp + kc0) = h0;
    *(bf16x8*)(khp + kc1) = h1;
    *(bf16x8*)(klp + kc0) = l0;
    *(bf16x8*)(klp + kc1) = l1;
    split44(vReg[0], vReg[1], h0, l0);
    split44(vReg[2], vReg[3], h1, l1);
    *(bf16x8*)(vhp + vc0) = h0;
    *(bf16x8*)(vhp + vc1) = h1;
    *(bf16x8*)(vlp + vc0) = l0;
    *(bf16x8*)(vlp + vc1) = l1;
    __syncthreads();  // staged tiles visible
    if (j0 + 32 < SEQ) {  // T14 prefetch of next tile
      const float* kp = kBase + (size_t)(j0 + 32) * DIMC;
      const float* vp = vBase + j0 + 32;
#pragma unroll
      for (int c = 0; c < 4; ++c) {
        kReg[c] = *(const f32x4*)(kp + c * 4);
        vReg[c] = *(const f32x4*)(vp + c * 4);
      }
    }
    // ---- QK^T (3-term) ----
    f32x4 s0 = zero4, s1 = zero4;
    __builtin_amdgcn_s_setprio(1);
#pragma unroll
    for (int kc = 0; kc < 4; ++kc) {
      const int cb = (kc * 64 + g * 16) ^ ((l16 & 7) << 4);
      bf16x8 kh0 = *(const bf16x8*)((char*)Kh + l16 * 256 + cb);
      bf16x8 kl0 = *(const bf16x8*)((char*)Kl + l16 * 256 + cb);
      bf16x8 kh1 = *(const bf16x8*)((char*)Kh + (16 + l16) * 256 + cb);
      bf16x8 kl1 = *(const bf16x8*)((char*)Kl + (16 + l16) * 256 + cb);
      s0 = __builtin_amdgcn_mfma_f32_16x16x32_bf16(ql[kc], kh0, s0, 0, 0, 0);
      s0 = __builtin_amdgcn_mfma_f32_16x16x32_bf16(qh[kc], kl0, s0, 0, 0, 0);
      s0 = __builtin_amdgcn_mfma_f32_16x16x32_bf16(qh[kc], kh0, s0, 0, 0, 0);
      s1 = __builtin_amdgcn_mfma_f32_16x16x32_bf16(ql[kc], kh1, s1, 0, 0, 0);
      s1 = __builtin_amdgcn_mfma_f32_16x16x32_bf16(qh[kc], kl1, s1, 0, 0, 0);
      s1 = __builtin_amdgcn_mfma_f32_16x16x32_bf16(qh[kc], kh1, s1, 0, 0, 0);
    }
    __builtin_amdgcn_s_setprio(0);
    // ---- online softmax ----
    float corr[4];
#pragma unroll
    for (int r = 0; r < 4; ++r) {
      float tm = fmaxf(s0[r], s1[r]);
#pragma unroll
      for (int m = 1; m < 16; m <<= 1) tm = fmaxf(tm, __shfl_xor(tm, m));
      float mn = fmaxf(mr[r], tm);
      corr[r] = __expf(mr[r] - mn);
      mr[r] = mn;
      float p0 = __expf(s0[r] - mn);
      float p1 = __expf(s1[r] - mn);
      lr[r] = lr[r] * corr[r] + p0 + p1;
      u16 p0h = f2bf(p0), p1h = f2bf(p1);
      Pah[wid][(g * 4 + r) * 40 + l16] = p0h;
      Pah[wid][(g * 4 + r) * 40 + 16 + l16] = p1h;
      Pal[wid][(g * 4 + r) * 40 + l16] = f2bf(p0 - bf2f(p0h));
      Pal[wid][(g * 4 + r) * 40 + 16 + l16] = f2bf(p1 - bf2f(p1h));
    }
#pragma unroll
    for (int db = 0; db < 8; ++db)
#pragma unroll
      for (int r = 0; r < 4; ++r) oacc[db][r] *= corr[r];
    // P write->read is same-wave LDS (per-wave region): compiler-inserted lgkmcnt orders it
    bf16x8 pfh = *(const bf16x8*)(&Pah[wid][l16 * 40 + g * 8]);
    bf16x8 pfl = *(const bf16x8*)(&Pal[wid][l16 * 40 + g * 8]);
    // ---- PV (3-term) ----
    __builtin_amdgcn_s_setprio(1);
#pragma unroll
    for (int db = 0; db < 8; ++db) {
      const int row = db * 16 + l16;
      const int cb = (g * 16) ^ ((row & 3) << 4);
      bf16x8 vh = *(const bf16x8*)((char*)Vh + row * 64 + cb);
      bf16x8 vl = *(const bf16x8*)((char*)Vl + row * 64 + cb);
      oacc[db] = __builtin_amdgcn_mfma_f32_16x16x32_bf16(pfl, vh, oacc[db], 0, 0, 0);
      oacc[db] = __builtin_amdgcn_mfma_f32_16x16x32_bf16(pfh, vl, oacc[db], 0, 0, 0);
      oacc[db] = __builtin_amdgcn_mfma_f32_16x16x32_bf16(pfh, vh, oacc[db], 0, 0, 0);
    }
    __builtin_amdgcn_s_setprio(0);
  }
#pragma unroll
  for (int r = 0; r < 4; ++r) {
#pragma unroll
    for (int m = 1; m < 16; m <<= 1) lr[r] += __shfl_xor(lr[r], m);
    lr[r] = 1.f / lr[r];
  }
#pragma unroll
  for (int db = 0; db < 8; ++db)
#pragma unroll
    for (int r = 0; r < 4; ++r)
      o[(size_t)(r0 + g * 4 + r) * DIMC + hOff + db * 16 + l16] = oacc[db][r] * lr[r];
}

// ---------------- final: out = g_mlp[col]*ff + img   (img aliases out; in-place) ----------------
__global__ __launch_bounds__(256) void k_final(const float* __restrict__ ff, const float* img,
                                               const float* __restrict__ mod, float* out) {
  const float4* gm = (const float4*)(mod + 5 * DIMC);
  const int total = SEQ * DIMC / 4;
  const int stride = gridDim.x * blockDim.x;
  for (int i = blockIdx.x * blockDim.x + threadIdx.x; i < total; i += stride) {
    int col4 = i & (DIMC / 4 - 1);
    float4 gv = gm[col4];
    float4 fv = ((const float4*)ff)[i];
    float4 iv = ((const float4*)img)[i];
    float4 ov;
    ov.x = gv.x * fv.x + iv.x;
    ov.y = gv.y * fv.y + iv.y;
    ov.z = gv.z * fv.z + iv.z;
    ov.w = gv.w * fv.w + iv.w;
    ((float4*)out)[i] = ov;
  }
}

extern "C" void kernel_launch(void* const* d_in, const int* in_sizes, int n_in, void* d_out, int out_size,
                              void* d_ws, size_t ws_size, hipStream_t stream) {
  (void)in_sizes; (void)n_in; (void)out_size; (void)ws_size;
  const float* image_tokens = (const float*)d_in[0];
  const float* adaln_input = (const float*)d_in[1];
  const float* W_ada = (const float*)d_in[2];
  const float* b_ada = (const float*)d_in[3];
  const float* Wq = (const float*)d_in[4];
  const float* bq = (const float*)d_in[5];
  const float* Wk = (const float*)d_in[6];
  const float* bk = (const float*)d_in[7];
  const float* Wv = (const float*)d_in[8];
  const float* bv = (const float*)d_in[9];
  const float* q_rms_w = (const float*)d_in[10];
  const float* k_rms_w = (const float*)d_in[11];
  const float* Wo = (const float*)d_in[12];
  const float* bo = (const float*)d_in[13];
  const float* gate_w = (const float*)d_in[14];
  const float* We1 = (const float*)d_in[15];
  const float* We3 = (const float*)d_in[16];
  const float* We2 = (const float*)d_in[17];
  const float* Ws1 = (const float*)d_in[18];
  const float* Ws3 = (const float*)d_in[19];
  const float* Ws2 = (const float*)d_in[20];

  // ---- workspace: ~166 MB, no aliasing ----
  char* cur = (char*)d_ws;
  auto alloc = [&](size_t n) {
    char* p = cur;
    cur += (n + 255) & ~(size_t)255;
    return p;
  };
  float* modv = (float*)alloc((size_t)MOD6 * 4);
  float* adap = (float*)alloc((size_t)16 * MOD6 * 4);
  float* comb = (float*)alloc((size_t)SEQ * NEXP * 4);
  float* xf = (float*)alloc((size_t)SEQ * DIMC * 4);    // f32 modulated x (attention)
  float* wTf = (float*)alloc((size_t)DIMC * DIMC * 4);  // f32 transposed attention weight
  float* tf = (float*)alloc((size_t)SEQ * DIMC * 4);    // f32 q_raw / k_raw scratch
  float* qf = (float*)alloc((size_t)SEQ * DIMC * 4);    // f32 q (rms'd, scaled)
  float* kf = (float*)alloc((size_t)SEQ * DIMC * 4);    // f32 k (rms'd)
  float* vtf = (float*)alloc((size_t)SEQ * DIMC * 4);   // f32 V^T
  float* aof = (float*)alloc((size_t)SEQ * DIMC * 4);   // f32 attention out
  u16* x_act = (u16*)alloc((size_t)SEQ * DIMC * 2);     // bf16 MoE input
  u16* wbuf = (u16*)alloc((size_t)HSH * DIMC * 2);      // bf16 MoE transpose buffer
  u16* H1G = (u16*)alloc((size_t)SEQ * HSH * 2);        // bf16 H1 -> G (in place)
  float* ff = (float*)alloc((size_t)SEQ * DIMC * 4);    // f32 FFN accumulator
  float* img = (float*)d_out;                           // written by MODE2 before any read

  dim3 blk(256);
  auto gemm3 = [&](int mode, const float* A, const float* BT, int M, int N, int K, float* Cf,
                   const float* bias, const float* gv, const float* resid) {
    dim3 grid(N / 128, M / 128);
    switch (mode) {
      case 0: k_gemm3<0><<<grid, blk, 0, stream>>>(A, BT, M, N, K, Cf, bias, gv, resid); break;
      case 2: k_gemm3<2><<<grid, blk, 0, stream>>>(A, BT, M, N, K, Cf, bias, gv, resid); break;
      default: k_gemm3<6><<<grid, blk, 0, stream>>>(A, BT, M, N, K, Cf, bias, gv, resid); break;
    }
  };
  auto gemm = [&](int mode, const u16* A, const u16* BT, int M, int N, int K, float* Cf, u16* Cb,
                  const float* bias, const u16* h1, const float* rs) {
    dim3 grid(N / 128, M / 128);
    switch (mode) {
      case 0: k_gemm<0><<<grid, blk, 0, stream>>>(A, BT, M, N, K, Cf, Cb, bias, h1, rs); break;
      case 1: k_gemm<1><<<grid, blk, 0, stream>>>(A, BT, M, N, K, Cf, Cb, bias, h1, rs); break;
      case 3: k_gemm<3><<<grid, blk, 0, stream>>>(A, BT, M, N, K, Cf, Cb, bias, h1, rs); break;
      default: k_gemm<4><<<grid, blk, 0, stream>>>(A, BT, M, N, K, Cf, Cb, bias, h1, rs); break;
    }
  };

  // adaLN modulation vector
  k_adaln_p<<<dim3(MOD6 / 256, 16), blk, 0, stream>>>(adaln_input, W_ada, adap);
  k_adaln_r<<<dim3(MOD6 / 256), blk, 0, stream>>>(adap, b_ada, modv);

  // ---- attention branch (f32-accurate via split-bf16 GEMMs) ----
  k_ln_modf<<<dim3(SEQ), blk, 0, stream>>>(image_tokens, modv, 0, DIMC, xf);
  k_transpose_f<<<dim3(DIMC / 32, DIMC / 32), blk, 0, stream>>>(Wq, wTf, DIMC, DIMC, DIMC);
  gemm3(0, xf, wTf, SEQ, DIMC, DIMC, tf, bq, nullptr, nullptr);
  k_rms_f32<<<dim3(SEQ), blk, 0, stream>>>(tf, q_rms_w, 0.08838834764831845f, qf);
  k_transpose_f<<<dim3(DIMC / 32, DIMC / 32), blk, 0, stream>>>(Wk, wTf, DIMC, DIMC, DIMC);
  gemm3(0, xf, wTf, SEQ, DIMC, DIMC, tf, bk, nullptr, nullptr);
  k_rms_f32<<<dim3(SEQ), blk, 0, stream>>>(tf, k_rms_w, 1.f, kf);
  k_transpose_f<<<dim3(DIMC / 32, DIMC / 32), blk, 0, stream>>>(Wv, wTf, DIMC, DIMC, DIMC);
  gemm3(6, xf, wTf, SEQ, DIMC, DIMC, vtf, bv, nullptr, nullptr);
  k_flash3<<<dim3(SEQ / 64, NHEAD), blk, 0, stream>>>(qf, kf, vtf, aof);
  k_transpose_f<<<dim3(DIMC / 32, DIMC / 32), blk, 0, stream>>>(Wo, wTf, DIMC, DIMC, DIMC);
  gemm3(2, aof, wTf, SEQ, DIMC, DIMC, img, bo, modv + 2 * DIMC, image_tokens);

  // ---- MoE branch (bf16; selection decided in f32 by k_gate) ----
  k_ln_mod<<<dim3(SEQ), blk, 0, stream>>>(img, modv, 3 * DIMC, 4 * DIMC, x_act);
  k_gate<<<dim3(SEQ), blk, 0, stream>>>(img, modv, gate_w, comb);
  bool first = true;
  for (int e = 0; e < NEXP; ++e) {
    for (int h = 0; h < 2; ++h) {
      const float* We1h = We1 + (size_t)e * DIMC * HIDC + (size_t)h * HSH;
      const float* We3h = We3 + (size_t)e * DIMC * HIDC + (size_t)h * HSH;
      const float* We2h = We2 + (size_t)e * HIDC * DIMC + (size_t)h * HSH * DIMC;
      k_transpose<<<dim3(HSH / 32, DIMC / 32), blk, 0, stream>>>(We1h, wbuf, DIMC, HSH, HIDC);
      gemm(1, x_act, wbuf, SEQ, HSH, DIMC, nullptr, H1G, nullptr, nullptr, nullptr);
      k_transpose<<<dim3(HSH / 32, DIMC / 32), blk, 0, stream>>>(We3h, wbuf, DIMC, HSH, HIDC);
      gemm(3, x_act, wbuf, SEQ, HSH, DIMC, nullptr, H1G, nullptr, H1G, comb + e);
      k_transpose<<<dim3(DIMC / 32, HSH / 32), blk, 0, stream>>>(We2h, wbuf, HSH, DIMC, DIMC);
      gemm(first ? 0 : 4, H1G, wbuf, SEQ, DIMC, HSH, ff, nullptr, nullptr, nullptr, nullptr);
      first = false;
    }
  }
  // shared expert
  k_transpose<<<dim3(HSH / 32, DIMC / 32), blk, 0, stream>>>(Ws1, wbuf, DIMC, HSH, HSH);
  gemm(1, x_act, wbuf, SEQ, HSH, DIMC, nullptr, H1G, nullptr, nullptr, nullptr);
  k_transpose<<<dim3(HSH / 32, DIMC / 32), blk, 0, stream>>>(Ws3, wbuf, DIMC, HSH, HSH);
  gemm(3, x_act, wbuf, SEQ, HSH, DIMC, nullptr, H1G, nullptr, H1G, nullptr);
  k_transpose<<<dim3(DIMC / 32, HSH / 32), blk, 0, stream>>>(Ws2, wbuf, HSH, DIMC, DIMC);
  gemm(4, H1G, wbuf, SEQ, DIMC, HSH, ff, nullptr, nullptr, nullptr, nullptr);

  k_final<<<dim3(1024), blk, 0, stream>>>(ff, img, modv, (float*)d_out);
}

// Round 6
// 1894.520 us; speedup vs baseline: 1.4923x; 1.2769x over previous
//
#include <hip/hip_runtime.h>
#include <hip/hip_bf16.h>

typedef unsigned short u16;
typedef __bf16 bf16x8 __attribute__((ext_vector_type(8)));
typedef float f32x4 __attribute__((ext_vector_type(4)));
typedef unsigned short u16x8 __attribute__((ext_vector_type(8)));

constexpr int DIMC = 2048;
constexpr int SEQ = 2048;
constexpr int NHEAD = 16;
constexpr int HDIM = 128;
constexpr int NEXP = 4;
constexpr int HIDC = 5632;
constexpr int HSH = 2816;
constexpr int MOD6 = 6 * DIMC;
constexpr int RSTRIDE = 2304;  // per-expert routing-list stride (2048 + pad headroom)

static __device__ __forceinline__ u16 f2bf(float f) {
  __hip_bfloat16 b = __float2bfloat16(f);
  return __builtin_bit_cast(u16, b);
}
static __device__ __forceinline__ float bf2f(u16 u) {
  unsigned int x = ((unsigned int)u) << 16;
  return __builtin_bit_cast(float, x);
}
static __device__ __forceinline__ float sigf(float x) { return 1.f / (1.f + __expf(-x)); }

static __device__ __forceinline__ void gload16(const void* src, void* dst) {
  __builtin_amdgcn_global_load_lds((const __attribute__((address_space(1))) void*)src,
                                   (__attribute__((address_space(3))) void*)dst, 16, 0, 0);
}

// split f32 8-vector (two f32x4) into hi/lo bf16x8: v ≈ h + l
static __device__ __forceinline__ void split44(f32x4 lo, f32x4 hi, bf16x8& h, bf16x8& l) {
#pragma unroll
  for (int e = 0; e < 4; ++e) {
    float f0 = lo[e];
    u16 h0 = f2bf(f0);
    h[e] = __builtin_bit_cast(__bf16, h0);
    l[e] = __builtin_bit_cast(__bf16, f2bf(f0 - bf2f(h0)));
    float f1 = hi[e];
    u16 h1 = f2bf(f1);
    h[4 + e] = __builtin_bit_cast(__bf16, h1);
    l[4 + e] = __builtin_bit_cast(__bf16, f2bf(f1 - bf2f(h1)));
  }
}

// block = 256 threads (4 waves); returns total across block to all threads
static __device__ __forceinline__ float blockSum(float v) {
#pragma unroll
  for (int m = 1; m < 64; m <<= 1) v += __shfl_xor(v, m);
  __shared__ float s[4];
  int w = threadIdx.x >> 6;
  if ((threadIdx.x & 63) == 0) s[w] = v;
  __syncthreads();
  float r = s[0] + s[1] + s[2] + s[3];
  __syncthreads();
  return r;
}

// ---------------- transpose f32 [R,C] (row stride ldin) -> bf16 [C,R] ----------------
__global__ __launch_bounds__(256) void k_transpose(const float* __restrict__ in, u16* __restrict__ out,
                                                   int R, int C, int ldin) {
  __shared__ __align__(16) float tile[32][33];
  int tx = threadIdx.x & 31, ty = threadIdx.x >> 5;
  int c0 = blockIdx.x * 32, r0 = blockIdx.y * 32;
#pragma unroll
  for (int i = 0; i < 32; i += 8)
    tile[ty + i][tx] = in[(size_t)(r0 + ty + i) * ldin + c0 + tx];
  __syncthreads();
#pragma unroll
  for (int i = 0; i < 32; i += 8)
    out[(size_t)(c0 + ty + i) * R + r0 + tx] = f2bf(tile[tx][ty + i]);
}

// ---------------- transpose f32 [R,C] -> f32 [C,R] (attention weights) ----------------
__global__ __launch_bounds__(256) void k_transpose_f(const float* __restrict__ in, float* __restrict__ out,
                                                     int R, int C, int ldin) {
  __shared__ __align__(16) float tile[32][33];
  int tx = threadIdx.x & 31, ty = threadIdx.x >> 5;
  int c0 = blockIdx.x * 32, r0 = blockIdx.y * 32;
#pragma unroll
  for (int i = 0; i < 32; i += 8)
    tile[ty + i][tx] = in[(size_t)(r0 + ty + i) * ldin + c0 + tx];
  __syncthreads();
#pragma unroll
  for (int i = 0; i < 32; i += 8)
    out[(size_t)(c0 + ty + i) * R + r0 + tx] = tile[tx][ty + i];
}

// ---------------- adaLN: mod = silu(a) @ W_ada + b_ada, split over 16 d-slices ----------------
__global__ __launch_bounds__(256) void k_adaln_p(const float* __restrict__ a, const float* __restrict__ W,
                                                 float* __restrict__ partial) {
  __shared__ float sa[128];
  int tid = threadIdx.x, slice = blockIdx.y;
  if (tid < 128) { float v = a[slice * 128 + tid]; sa[tid] = v * sigf(v); }
  __syncthreads();
  int j = blockIdx.x * 256 + tid;
  float acc = 0.f;
#pragma unroll 4
  for (int d = 0; d < 128; ++d) acc += sa[d] * W[(size_t)(slice * 128 + d) * MOD6 + j];
  partial[(size_t)slice * MOD6 + j] = acc;
}
__global__ __launch_bounds__(256) void k_adaln_r(const float* __restrict__ partial, const float* __restrict__ b,
                                                 float* __restrict__ mod) {
  int j = blockIdx.x * 256 + threadIdx.x;
  float acc = b[j];
#pragma unroll
  for (int s = 0; s < 16; ++s) acc += partial[(size_t)s * MOD6 + j];
  mod[j] = acc;
}

// ---------------- LayerNorm + adaLN modulate -> f32 (attention x) ----------------
__global__ __launch_bounds__(256) void k_ln_modf(const float* __restrict__ X, const float* __restrict__ mod,
                                                 int shOff, int scOff, float* __restrict__ out) {
  int row = blockIdx.x, tid = threadIdx.x;
  const float4* x4 = (const float4*)(X + (size_t)row * DIMC);
  float4 v0 = x4[tid * 2], v1 = x4[tid * 2 + 1];
  float s = v0.x + v0.y + v0.z + v0.w + v1.x + v1.y + v1.z + v1.w;
  float ss = v0.x * v0.x + v0.y * v0.y + v0.z * v0.z + v0.w * v0.w +
             v1.x * v1.x + v1.y * v1.y + v1.z * v1.z + v1.w * v1.w;
  s = blockSum(s);
  ss = blockSum(ss);
  float mean = s * (1.f / DIMC);
  float var = ss * (1.f / DIMC) - mean * mean;
  float rstd = rsqrtf(var + 1e-6f);
  const float* sh = mod + shOff;
  const float* sc = mod + scOff;
  int c = tid * 8;
  float xv[8] = {v0.x, v0.y, v0.z, v0.w, v1.x, v1.y, v1.z, v1.w};
  float ov[8];
#pragma unroll
  for (int e = 0; e < 8; ++e) ov[e] = (xv[e] - mean) * rstd * (1.f + sc[c + e]) + sh[c + e];
  float4 o0 = {ov[0], ov[1], ov[2], ov[3]}, o1 = {ov[4], ov[5], ov[6], ov[7]};
  float4* y4 = (float4*)(out + (size_t)row * DIMC);
  y4[tid * 2] = o0;
  y4[tid * 2 + 1] = o1;
}

// ---------------- LayerNorm + adaLN modulate -> bf16 (MoE x_act) ----------------
__global__ __launch_bounds__(256) void k_ln_mod(const float* __restrict__ X, const float* __restrict__ mod,
                                                int shOff, int scOff, u16* __restrict__ out) {
  int row = blockIdx.x, tid = threadIdx.x;
  const float4* x4 = (const float4*)(X + (size_t)row * DIMC);
  float4 v0 = x4[tid * 2], v1 = x4[tid * 2 + 1];
  float s = v0.x + v0.y + v0.z + v0.w + v1.x + v1.y + v1.z + v1.w;
  float ss = v0.x * v0.x + v0.y * v0.y + v0.z * v0.z + v0.w * v0.w +
             v1.x * v1.x + v1.y * v1.y + v1.z * v1.z + v1.w * v1.w;
  s = blockSum(s);
  ss = blockSum(ss);
  float mean = s * (1.f / DIMC);
  float var = ss * (1.f / DIMC) - mean * mean;
  float rstd = rsqrtf(var + 1e-6f);
  const float* sh = mod + shOff;
  const float* sc = mod + scOff;
  int c = tid * 8;
  float xv[8] = {v0.x, v0.y, v0.z, v0.w, v1.x, v1.y, v1.z, v1.w};
  u16x8 o;
#pragma unroll
  for (int e = 0; e < 8; ++e) o[e] = f2bf((xv[e] - mean) * rstd * (1.f + sc[c + e]) + sh[c + e]);
  *(u16x8*)(out + (size_t)row * DIMC + c) = o;
}

// ---------------- RMSNorm f32 in -> f32 out, * weight * scale ----------------
__global__ __launch_bounds__(256) void k_rms_f32(const float* __restrict__ X, const float* __restrict__ w,
                                                 float scale, float* __restrict__ out) {
  int row = blockIdx.x, tid = threadIdx.x;
  const float4* x4 = (const float4*)(X + (size_t)row * DIMC);
  float4 v0 = x4[tid * 2], v1 = x4[tid * 2 + 1];
  float ss = v0.x * v0.x + v0.y * v0.y + v0.z * v0.z + v0.w * v0.w +
             v1.x * v1.x + v1.y * v1.y + v1.z * v1.z + v1.w * v1.w;
  ss = blockSum(ss);
  float rstd = rsqrtf(ss * (1.f / DIMC) + 1e-5f) * scale;
  int c = tid * 8;
  float xv[8] = {v0.x, v0.y, v0.z, v0.w, v1.x, v1.y, v1.z, v1.w};
  float ov[8];
#pragma unroll
  for (int e = 0; e < 8; ++e) ov[e] = xv[e] * rstd * w[c + e];
  float4 o0 = {ov[0], ov[1], ov[2], ov[3]}, o1 = {ov[4], ov[5], ov[6], ov[7]};
  float4* y4 = (float4*)(out + (size_t)row * DIMC);
  y4[tid * 2] = o0;
  y4[tid * 2 + 1] = o1;
}

// ---------------- gating: recompute LN+mod in f32, softmax over 4, top-2 -> comb[n][4] ----------------
__global__ __launch_bounds__(256) void k_gate(const float* __restrict__ img, const float* __restrict__ mod,
                                              const float* __restrict__ gw, float* __restrict__ comb) {
  int n = blockIdx.x, tid = threadIdx.x;
  const float4* x4 = (const float4*)(img + (size_t)n * DIMC);
  float4 v0 = x4[tid * 2], v1 = x4[tid * 2 + 1];
  float s = v0.x + v0.y + v0.z + v0.w + v1.x + v1.y + v1.z + v1.w;
  float ss = v0.x * v0.x + v0.y * v0.y + v0.z * v0.z + v0.w * v0.w +
             v1.x * v1.x + v1.y * v1.y + v1.z * v1.z + v1.w * v1.w;
  s = blockSum(s);
  ss = blockSum(ss);
  float mean = s * (1.f / DIMC);
  float var = ss * (1.f / DIMC) - mean * mean;
  float rstd = rsqrtf(var + 1e-6f);
  const float* sh = mod + 3 * DIMC;
  const float* sc = mod + 4 * DIMC;
  int c = tid * 8;
  float xv[8] = {v0.x, v0.y, v0.z, v0.w, v1.x, v1.y, v1.z, v1.w};
  float y[8];
#pragma unroll
  for (int e = 0; e < 8; ++e) y[e] = (xv[e] - mean) * rstd * (1.f + sc[c + e]) + sh[c + e];
  float accs[NEXP];
#pragma unroll
  for (int ex = 0; ex < NEXP; ++ex) {
    float a = 0.f;
#pragma unroll
    for (int e = 0; e < 8; ++e) a += y[e] * gw[(size_t)ex * DIMC + c + e];
    accs[ex] = blockSum(a);
  }
  if (tid == 0) {
    float mx = fmaxf(fmaxf(accs[0], accs[1]), fmaxf(accs[2], accs[3]));
    float ex0 = __expf(accs[0] - mx), ex1 = __expf(accs[1] - mx);
    float ex2 = __expf(accs[2] - mx), ex3 = __expf(accs[3] - mx);
    float inv = 1.f / (ex0 + ex1 + ex2 + ex3);
    float v[4] = {ex0 * inv, ex1 * inv, ex2 * inv, ex3 * inv};
    int i1 = 0;
    for (int e = 1; e < 4; ++e)
      if (v[e] > v[i1]) i1 = e;
    int i2 = -1;
    for (int e = 0; e < 4; ++e) {
      if (e == i1) continue;
      if (i2 < 0 || v[e] > v[i2]) i2 = e;
    }
    for (int e = 0; e < 4; ++e) comb[(size_t)n * 4 + e] = (e == i1 || e == i2) ? v[e] : 0.f;
  }
}

// ---------------- routing: deterministic per-expert token lists (1 block, wave e = expert e) ----------------
__global__ __launch_bounds__(256) void k_route(const float* __restrict__ comb, int* __restrict__ gidx,
                                               float* __restrict__ cw, int* __restrict__ Mpad) {
  int wid = threadIdx.x >> 6, lane = threadIdx.x & 63;
  int base = 0;
  for (int c = 0; c < SEQ; c += 64) {
    int n = c + lane;
    float w = comb[(size_t)n * NEXP + wid];
    bool sel = w > 0.f;
    unsigned long long mask = __ballot(sel);
    int pos = __popcll(mask & ((1ull << lane) - 1ull));
    if (sel) {
      gidx[wid * RSTRIDE + base + pos] = n;
      cw[wid * RSTRIDE + base + pos] = w;
    }
    base += __popcll(mask);
  }
  int padded = (base + 127) & ~127;
  for (int i = base + lane; i < padded; i += 64) {
    gidx[wid * RSTRIDE + i] = -1;
    cw[wid * RSTRIDE + i] = 0.f;
  }
  if (lane == 0) Mpad[wid] = padded;
}

// ---------------- bf16 GEMM (dense, shared expert): C[M,N] = A @ BT^T ----------------
// MODE 0: Cf = acc+bias   1: Cb = bf16(acc+bias)
// MODE 3: Cb = bf16( silu(h1)*acc )  (h1 bf16, may alias Cb)
// MODE 4: Cf += acc
template <int MODE>
__global__ __launch_bounds__(256, 2) void k_gemm(const u16* __restrict__ A, const u16* __restrict__ BT,
                                                 int M, int N, int K, float* __restrict__ Cf,
                                                 u16* __restrict__ Cb, const float* __restrict__ bias,
                                                 const u16* __restrict__ h1) {
  __shared__ __align__(16) u16 As[4096], Bs[4096];
  const int tid = threadIdx.x, wid = tid >> 6, lane = tid & 63;
  const int l16 = lane & 15, g = lane >> 4;
  const int wr = wid >> 1, wc = wid & 1;
  const int m0 = blockIdx.y * 128, n0 = blockIdx.x * 128;
  const int srow = lane >> 2, scol = (lane & 3) * 8;
  const u16* aS0 = A + (size_t)(m0 + wid * 32 + srow) * K + scol;
  const u16* aS1 = aS0 + (size_t)16 * K;
  const u16* bS0 = BT + (size_t)(n0 + wid * 32 + srow) * K + scol;
  const u16* bS1 = bS0 + (size_t)16 * K;
  u16* aD0 = &As[wid * 1024];
  u16* aD1 = aD0 + 512;
  u16* bD0 = &Bs[wid * 1024];
  u16* bD1 = bD0 + 512;

  const f32x4 zero4 = {0.f, 0.f, 0.f, 0.f};
  f32x4 acc[4][4];
#pragma unroll
  for (int mi = 0; mi < 4; ++mi)
#pragma unroll
    for (int ni = 0; ni < 4; ++ni) acc[mi][ni] = zero4;

  for (int k0 = 0; k0 < K; k0 += 32) {
    __syncthreads();
    gload16(aS0 + k0, aD0);
    gload16(aS1 + k0, aD1);
    gload16(bS0 + k0, bD0);
    gload16(bS1 + k0, bD1);
    __syncthreads();
    bf16x8 af[4], bfr[4];
#pragma unroll
    for (int mi = 0; mi < 4; ++mi)
      af[mi] = *(const bf16x8*)(&As[(wr * 64 + mi * 16 + l16) * 32 + g * 8]);
#pragma unroll
    for (int ni = 0; ni < 4; ++ni)
      bfr[ni] = *(const bf16x8*)(&Bs[(wc * 64 + ni * 16 + l16) * 32 + g * 8]);
#pragma unroll
    for (int mi = 0; mi < 4; ++mi)
#pragma unroll
      for (int ni = 0; ni < 4; ++ni)
        acc[mi][ni] = __builtin_amdgcn_mfma_f32_16x16x32_bf16(af[mi], bfr[ni], acc[mi][ni], 0, 0, 0);
  }

#pragma unroll
  for (int mi = 0; mi < 4; ++mi) {
#pragma unroll
    for (int ni = 0; ni < 4; ++ni) {
      const int col = n0 + wc * 64 + ni * 16 + l16;
      float bv = 0.f;
      if (MODE == 0 || MODE == 1) {
        if (bias) bv = bias[col];
      }
#pragma unroll
      for (int r = 0; r < 4; ++r) {
        const int row = m0 + wr * 64 + mi * 16 + g * 4 + r;
        const size_t idx = (size_t)row * N + col;
        float v = acc[mi][ni][r] + bv;
        if constexpr (MODE == 0) {
          Cf[idx] = v;
        } else if constexpr (MODE == 1) {
          Cb[idx] = f2bf(v);
        } else if constexpr (MODE == 3) {
          float hv = bf2f(h1[idx]);
          float sw = hv * sigf(hv);
          Cb[idx] = f2bf(sw * v);
        } else {
          Cf[idx] += v;
        }
      }
    }
  }
}

// ---------------- routed bf16 GEMM (experts) ----------------
// RM 0: H1[slot][col] = bf16(acc)                 A-rows gathered via gidxE
// RM 1: G[slot][col]  = bf16(silu(h1)*acc*cwE[slot])   A-rows gathered via gidxE
// RM 2: t=gidxE[slot]; if(t>=0) ff[t*N+col] += acc     A linear (slot space)
template <int RM>
__global__ __launch_bounds__(256, 2) void k_gemmR(const u16* __restrict__ A, const u16* __restrict__ BT,
                                                  int N, int K, const int* __restrict__ gidxE,
                                                  const float* __restrict__ cwE,
                                                  const int* __restrict__ MpE, u16* __restrict__ Cb,
                                                  const u16* __restrict__ h1, float* __restrict__ ff) {
  const int m0 = blockIdx.y * 128;
  if (m0 >= *MpE) return;  // data-dependent early exit (Mpad is a multiple of 128)
  __shared__ __align__(16) u16 As[4096], Bs[4096];
  const int tid = threadIdx.x, wid = tid >> 6, lane = tid & 63;
  const int l16 = lane & 15, g = lane >> 4;
  const int wr = wid >> 1, wc = wid & 1;
  const int n0 = blockIdx.x * 128;
  const int srow = lane >> 2, scol = (lane & 3) * 8;
  const int slot0 = m0 + wid * 32 + srow;
  int row0, row1;
  if constexpr (RM == 2) {
    row0 = slot0;
    row1 = slot0 + 16;
  } else {
    int t0 = gidxE[slot0], t1 = gidxE[slot0 + 16];
    row0 = t0 < 0 ? 0 : t0;  // pad slots read token 0; masked by cw=0 / store-skip
    row1 = t1 < 0 ? 0 : t1;
  }
  const u16* aS0 = A + (size_t)row0 * K + scol;
  const u16* aS1 = A + (size_t)row1 * K + scol;
  const u16* bS0 = BT + (size_t)(n0 + wid * 32 + srow) * K + scol;
  const u16* bS1 = bS0 + (size_t)16 * K;
  u16* aD0 = &As[wid * 1024];
  u16* aD1 = aD0 + 512;
  u16* bD0 = &Bs[wid * 1024];
  u16* bD1 = bD0 + 512;

  const f32x4 zero4 = {0.f, 0.f, 0.f, 0.f};
  f32x4 acc[4][4];
#pragma unroll
  for (int mi = 0; mi < 4; ++mi)
#pragma unroll
    for (int ni = 0; ni < 4; ++ni) acc[mi][ni] = zero4;

  for (int k0 = 0; k0 < K; k0 += 32) {
    __syncthreads();
    gload16(aS0 + k0, aD0);
    gload16(aS1 + k0, aD1);
    gload16(bS0 + k0, bD0);
    gload16(bS1 + k0, bD1);
    __syncthreads();
    bf16x8 af[4], bfr[4];
#pragma unroll
    for (int mi = 0; mi < 4; ++mi)
      af[mi] = *(const bf16x8*)(&As[(wr * 64 + mi * 16 + l16) * 32 + g * 8]);
#pragma unroll
    for (int ni = 0; ni < 4; ++ni)
      bfr[ni] = *(const bf16x8*)(&Bs[(wc * 64 + ni * 16 + l16) * 32 + g * 8]);
#pragma unroll
    for (int mi = 0; mi < 4; ++mi)
#pragma unroll
      for (int ni = 0; ni < 4; ++ni)
        acc[mi][ni] = __builtin_amdgcn_mfma_f32_16x16x32_bf16(af[mi], bfr[ni], acc[mi][ni], 0, 0, 0);
  }

#pragma unroll
  for (int mi = 0; mi < 4; ++mi) {
#pragma unroll
    for (int ni = 0; ni < 4; ++ni) {
      const int col = n0 + wc * 64 + ni * 16 + l16;
#pragma unroll
      for (int r = 0; r < 4; ++r) {
        const int slot = m0 + wr * 64 + mi * 16 + g * 4 + r;
        const size_t idx = (size_t)slot * N + col;
        float v = acc[mi][ni][r];
        if constexpr (RM == 0) {
          Cb[idx] = f2bf(v);
        } else if constexpr (RM == 1) {
          float hv = bf2f(h1[idx]);
          float sw = hv * sigf(hv);
          Cb[idx] = f2bf(sw * v * cwE[slot]);
        } else {
          int t = gidxE[slot];
          if (t >= 0) ff[(size_t)t * N + col] += v;
        }
      }
    }
  }
}

// ---------------- split-precision GEMM: reg-stage + pre-split hi/lo LDS, stride-80 rows ----------------
// MODE 0: Cf = acc+bias
// MODE 2: Cf = (acc+bias)*gvec[col] + resid
// MODE 6: Cf[col*M+row] = acc+bias   (transposed f32 store, for V^T)
template <int MODE>
__global__ __launch_bounds__(256, 2) void k_gemm3(const float* __restrict__ A, const float* __restrict__ BT,
                                                  int M, int N, int K, float* __restrict__ Cf,
                                                  const float* __restrict__ bias,
                                                  const float* __restrict__ gvec,
                                                  const float* __restrict__ resid) {
  // [128] rows x 80B (64B payload + 16B pad): bank base cycles period-8 -> conflict-free reads
  __shared__ __align__(16) u16 Ah[128 * 40], Al[128 * 40], Bh[128 * 40], Bl[128 * 40];
  const int tid = threadIdx.x, wid = tid >> 6, lane = tid & 63;
  const int l16 = lane & 15, g = lane >> 4;
  const int wr = wid >> 1, wc = wid & 1;
  const int m0 = blockIdx.y * 128, n0 = blockIdx.x * 128;

  const int srow = tid >> 1, se0 = (tid & 1) * 16;
  char* ahp = (char*)Ah + srow * 80 + se0 * 2;
  char* alp = (char*)Al + srow * 80 + se0 * 2;
  char* bhp = (char*)Bh + srow * 80 + se0 * 2;
  char* blp = (char*)Bl + srow * 80 + se0 * 2;
  const float* aS = A + (size_t)(m0 + srow) * K + se0;
  const float* bS = BT + (size_t)(n0 + srow) * K + se0;

  f32x4 ar[4], br[4];
#pragma unroll
  for (int c = 0; c < 4; ++c) {
    ar[c] = *(const f32x4*)(aS + c * 4);
    br[c] = *(const f32x4*)(bS + c * 4);
  }

  const f32x4 zero4 = {0.f, 0.f, 0.f, 0.f};
  f32x4 acc[4][4];
#pragma unroll
  for (int mi = 0; mi < 4; ++mi)
#pragma unroll
    for (int ni = 0; ni < 4; ++ni) acc[mi][ni] = zero4;

  for (int k0 = 0; k0 < K; k0 += 32) {
    __syncthreads();
    bf16x8 h0, l0, h1, l1;
    split44(ar[0], ar[1], h0, l0);
    split44(ar[2], ar[3], h1, l1);
    *(bf16x8*)(ahp) = h0;
    *(bf16x8*)(ahp + 16) = h1;
    *(bf16x8*)(alp) = l0;
    *(bf16x8*)(alp + 16) = l1;
    split44(br[0], br[1], h0, l0);
    split44(br[2], br[3], h1, l1);
    *(bf16x8*)(bhp) = h0;
    *(bf16x8*)(bhp + 16) = h1;
    *(bf16x8*)(blp) = l0;
    *(bf16x8*)(blp + 16) = l1;
    __syncthreads();
    if (k0 + 32 < K) {  // T14: issue next tile's loads under the MFMAs
#pragma unroll
      for (int c = 0; c < 4; ++c) {
        ar[c] = *(const f32x4*)(aS + k0 + 32 + c * 4);
        br[c] = *(const f32x4*)(bS + k0 + 32 + c * 4);
      }
    }
    bf16x8 bhf[4], blf[4];
#pragma unroll
    for (int ni = 0; ni < 4; ++ni) {
      const int rb = wc * 64 + ni * 16 + l16;
      bhf[ni] = *(const bf16x8*)((char*)Bh + rb * 80 + g * 16);
      blf[ni] = *(const bf16x8*)((char*)Bl + rb * 80 + g * 16);
    }
#pragma unroll
    for (int mi = 0; mi < 4; ++mi) {
      const int ra = wr * 64 + mi * 16 + l16;
      bf16x8 ahf = *(const bf16x8*)((char*)Ah + ra * 80 + g * 16);
      bf16x8 alf = *(const bf16x8*)((char*)Al + ra * 80 + g * 16);
#pragma unroll
      for (int ni = 0; ni < 4; ++ni) {
        acc[mi][ni] = __builtin_amdgcn_mfma_f32_16x16x32_bf16(alf, bhf[ni], acc[mi][ni], 0, 0, 0);
        acc[mi][ni] = __builtin_amdgcn_mfma_f32_16x16x32_bf16(ahf, blf[ni], acc[mi][ni], 0, 0, 0);
        acc[mi][ni] = __builtin_amdgcn_mfma_f32_16x16x32_bf16(ahf, bhf[ni], acc[mi][ni], 0, 0, 0);
      }
    }
  }

#pragma unroll
  for (int mi = 0; mi < 4; ++mi) {
#pragma unroll
    for (int ni = 0; ni < 4; ++ni) {
      const int col = n0 + wc * 64 + ni * 16 + l16;
      float bv = bias ? bias[col] : 0.f;
#pragma unroll
      for (int r = 0; r < 4; ++r) {
        const int row = m0 + wr * 64 + mi * 16 + g * 4 + r;
        float v = acc[mi][ni][r] + bv;
        if constexpr (MODE == 0) {
          Cf[(size_t)row * N + col] = v;
        } else if constexpr (MODE == 2) {
          Cf[(size_t)row * N + col] = v * gvec[col] + resid[(size_t)row * N + col];
        } else {
          Cf[(size_t)col * M + row] = v;
        }
      }
    }
  }
}

// ---------------- flash attention: block-staged pre-split K/V in LDS ----------------
// q,k [S,DIM] f32 (q pre-scaled), vt [DIM,S] f32
__global__ __launch_bounds__(256, 2) void k_flash3(const float* __restrict__ q, const float* __restrict__ kk,
                                                   const float* __restrict__ vt, float* __restrict__ o) {
  // K tiles [32][128] u16 (256B rows): data(r,d) at byte r*256 + ((d*2) ^ ((r&7)<<4)) -- reads conflict-free
  // V^T tiles [128] rows x 80B (64B payload): conflict-free reads by stride
  __shared__ __align__(16) u16 Kh[4096], Kl[4096], Vh[128 * 40], Vl[128 * 40];
  __shared__ __align__(16) u16 Pah[4][16 * 40], Pal[4][16 * 40];
  const int tid = threadIdx.x, wid = tid >> 6, lane = tid & 63;
  const int l16 = lane & 15, g = lane >> 4;
  const int h = blockIdx.y;
  const int r0 = blockIdx.x * 64 + wid * 16;
  const size_t hOff = (size_t)h * HDIM;

  bf16x8 qh[4], ql[4];
#pragma unroll
  for (int kc = 0; kc < 4; ++kc) {
    const float* qp = q + (size_t)(r0 + l16) * DIMC + hOff + kc * 32 + g * 8;
    split44(*(const f32x4*)qp, *(const f32x4*)(qp + 4), qh[kc], ql[kc]);
  }

  // staging geometry
  const int kr = tid >> 3, ke0 = (tid & 7) * 16;  // K: row 0..31, 16-elem chunk
  const int kswz = (kr & 7) << 4;
  const int kc0 = (ke0 * 2) ^ kswz, kc1 = (ke0 * 2 + 16) ^ kswz;
  char* khp = (char*)Kh + kr * 256;
  char* klp = (char*)Kl + kr * 256;
  const float* kBase = kk + (size_t)kr * DIMC + hOff + ke0;
  const int vr = tid >> 1, ve0 = (tid & 1) * 16;  // V: row(d) 0..127, 16-elem chunk
  char* vhp = (char*)Vh + vr * 80 + ve0 * 2;
  char* vlp = (char*)Vl + vr * 80 + ve0 * 2;
  const float* vBase = vt + (size_t)(hOff + vr) * SEQ + ve0;

  f32x4 kReg[4], vReg[4];
#pragma unroll
  for (int c = 0; c < 4; ++c) {
    kReg[c] = *(const f32x4*)(kBase + c * 4);
    vReg[c] = *(const f32x4*)(vBase + c * 4);
  }

  const f32x4 zero4 = {0.f, 0.f, 0.f, 0.f};
  f32x4 oacc[8];
#pragma unroll
  for (int db = 0; db < 8; ++db) oacc[db] = zero4;
  float mr[4], lr[4];
#pragma unroll
  for (int r = 0; r < 4; ++r) {
    mr[r] = -3.0e38f;
    lr[r] = 0.f;
  }

  for (int j0 = 0; j0 < SEQ; j0 += 32) {
    __syncthreads();  // all waves done reading prior K/V tiles
    bf16x8 h0, l0, h1, l1;
    split44(kReg[0], kReg[1], h0, l0);
    split44(kReg[2], kReg[3], h1, l1);
    *(bf16x8*)(khp + kc0) = h0;
    *(bf16x8*)(khp + kc1) = h1;
    *(bf16x8*)(klp + kc0) = l0;
    *(bf16x8*)(klp + kc1) = l1;
    split44(vReg[0], vReg[1], h0, l0);
    split44(vReg[2], vReg[3], h1, l1);
    *(bf16x8*)(vhp) = h0;
    *(bf16x8*)(vhp + 16) = h1;
    *(bf16x8*)(vlp) = l0;
    *(bf16x8*)(vlp + 16) = l1;
    __syncthreads();  // staged tiles visible
    if (j0 + 32 < SEQ) {  // T14 prefetch of next tile
      const float* kp = kBase + (size_t)(j0 + 32) * DIMC;
      const float* vp = vBase + j0 + 32;
#pragma unroll
      for (int c = 0; c < 4; ++c) {
        kReg[c] = *(const f32x4*)(kp + c * 4);
        vReg[c] = *(const f32x4*)(vp + c * 4);
      }
    }
    // ---- QK^T (3-term) ----
    f32x4 s0 = zero4, s1 = zero4;
    __builtin_amdgcn_s_setprio(1);
#pragma unroll
    for (int kc = 0; kc < 4; ++kc) {
      const int cb = (kc * 64 + g * 16) ^ ((l16 & 7) << 4);
      bf16x8 kh0 = *(const bf16x8*)((char*)Kh + l16 * 256 + cb);
      bf16x8 kl0 = *(const bf16x8*)((char*)Kl + l16 * 256 + cb);
      bf16x8 kh1 = *(const bf16x8*)((char*)Kh + (16 + l16) * 256 + cb);
      bf16x8 kl1 = *(const bf16x8*)((char*)Kl + (16 + l16) * 256 + cb);
      s0 = __builtin_amdgcn_mfma_f32_16x16x32_bf16(ql[kc], kh0, s0, 0, 0, 0);
      s0 = __builtin_amdgcn_mfma_f32_16x16x32_bf16(qh[kc], kl0, s0, 0, 0, 0);
      s0 = __builtin_amdgcn_mfma_f32_16x16x32_bf16(qh[kc], kh0, s0, 0, 0, 0);
      s1 = __builtin_amdgcn_mfma_f32_16x16x32_bf16(ql[kc], kh1, s1, 0, 0, 0);
      s1 = __builtin_amdgcn_mfma_f32_16x16x32_bf16(qh[kc], kl1, s1, 0, 0, 0);
      s1 = __builtin_amdgcn_mfma_f32_16x16x32_bf16(qh[kc], kh1, s1, 0, 0, 0);
    }
    __builtin_amdgcn_s_setprio(0);
    // ---- online softmax ----
    float corr[4];
#pragma unroll
    for (int r = 0; r < 4; ++r) {
      float tm = fmaxf(s0[r], s1[r]);
#pragma unroll
      for (int m = 1; m < 16; m <<= 1) tm = fmaxf(tm, __shfl_xor(tm, m));
      float mn = fmaxf(mr[r], tm);
      corr[r] = __expf(mr[r] - mn);
      mr[r] = mn;
      float p0 = __expf(s0[r] - mn);
      float p1 = __expf(s1[r] - mn);
      lr[r] = lr[r] * corr[r] + p0 + p1;
      u16 p0h = f2bf(p0), p1h = f2bf(p1);
      Pah[wid][(g * 4 + r) * 40 + l16] = p0h;
      Pah[wid][(g * 4 + r) * 40 + 16 + l16] = p1h;
      Pal[wid][(g * 4 + r) * 40 + l16] = f2bf(p0 - bf2f(p0h));
      Pal[wid][(g * 4 + r) * 40 + 16 + l16] = f2bf(p1 - bf2f(p1h));
    }
#pragma unroll
    for (int db = 0; db < 8; ++db)
#pragma unroll
      for (int r = 0; r < 4; ++r) oacc[db][r] *= corr[r];
    // P write->read is same-wave LDS: compiler-inserted lgkmcnt orders it
    bf16x8 pfh = *(const bf16x8*)(&Pah[wid][l16 * 40 + g * 8]);
    bf16x8 pfl = *(const bf16x8*)(&Pal[wid][l16 * 40 + g * 8]);
    // ---- PV (3-term) ----
    __builtin_amdgcn_s_setprio(1);
#pragma unroll
    for (int db = 0; db < 8; ++db) {
      const int row = db * 16 + l16;
      bf16x8 vh = *(const bf16x8*)((char*)Vh + row * 80 + g * 16);
      bf16x8 vl = *(const bf16x8*)((char*)Vl + row * 80 + g * 16);
      oacc[db] = __builtin_amdgcn_mfma_f32_16x16x32_bf16(pfl, vh, oacc[db], 0, 0, 0);
      oacc[db] = __builtin_amdgcn_mfma_f32_16x16x32_bf16(pfh, vl, oacc[db], 0, 0, 0);
      oacc[db] = __builtin_amdgcn_mfma_f32_16x16x32_bf16(pfh, vh, oacc[db], 0, 0, 0);
    }
    __builtin_amdgcn_s_setprio(0);
  }
#pragma unroll
  for (int r = 0; r < 4; ++r) {
#pragma unroll
    for (int m = 1; m < 16; m <<= 1) lr[r] += __shfl_xor(lr[r], m);
    lr[r] = 1.f / lr[r];
  }
#pragma unroll
  for (int db = 0; db < 8; ++db)
#pragma unroll
    for (int r = 0; r < 4; ++r)
      o[(size_t)(r0 + g * 4 + r) * DIMC + hOff + db * 16 + l16] = oacc[db][r] * lr[r];
}

// ---------------- final: out = g_mlp[col]*ff + img   (img aliases out; in-place) ----------------
__global__ __launch_bounds__(256) void k_final(const float* __restrict__ ff, const float* img,
                                               const float* __restrict__ mod, float* out) {
  const float4* gm = (const float4*)(mod + 5 * DIMC);
  const int total = SEQ * DIMC / 4;
  const int stride = gridDim.x * blockDim.x;
  for (int i = blockIdx.x * blockDim.x + threadIdx.x; i < total; i += stride) {
    int col4 = i & (DIMC / 4 - 1);
    float4 gv = gm[col4];
    float4 fv = ((const float4*)ff)[i];
    float4 iv = ((const float4*)img)[i];
    float4 ov;
    ov.x = gv.x * fv.x + iv.x;
    ov.y = gv.y * fv.y + iv.y;
    ov.z = gv.z * fv.z + iv.z;
    ov.w = gv.w * fv.w + iv.w;
    ((float4*)out)[i] = ov;
  }
}

extern "C" void kernel_launch(void* const* d_in, const int* in_sizes, int n_in, void* d_out, int out_size,
                              void* d_ws, size_t ws_size, hipStream_t stream) {
  (void)in_sizes; (void)n_in; (void)out_size; (void)ws_size;
  const float* image_tokens = (const float*)d_in[0];
  const float* adaln_input = (const float*)d_in[1];
  const float* W_ada = (const float*)d_in[2];
  const float* b_ada = (const float*)d_in[3];
  const float* Wq = (const float*)d_in[4];
  const float* bq = (const float*)d_in[5];
  const float* Wk = (const float*)d_in[6];
  const float* bk = (const float*)d_in[7];
  const float* Wv = (const float*)d_in[8];
  const float* bv = (const float*)d_in[9];
  const float* q_rms_w = (const float*)d_in[10];
  const float* k_rms_w = (const float*)d_in[11];
  const float* Wo = (const float*)d_in[12];
  const float* bo = (const float*)d_in[13];
  const float* gate_w = (const float*)d_in[14];
  const float* We1 = (const float*)d_in[15];
  const float* We3 = (const float*)d_in[16];
  const float* We2 = (const float*)d_in[17];
  const float* Ws1 = (const float*)d_in[18];
  const float* Ws3 = (const float*)d_in[19];
  const float* Ws2 = (const float*)d_in[20];

  // ---- workspace: ~190 MB, no aliasing ----
  char* cur = (char*)d_ws;
  auto alloc = [&](size_t n) {
    char* p = cur;
    cur += (n + 255) & ~(size_t)255;
    return p;
  };
  float* modv = (float*)alloc((size_t)MOD6 * 4);
  float* adap = (float*)alloc((size_t)16 * MOD6 * 4);
  float* comb = (float*)alloc((size_t)SEQ * NEXP * 4);
  int* gidx = (int*)alloc((size_t)NEXP * RSTRIDE * 4);
  float* cw = (float*)alloc((size_t)NEXP * RSTRIDE * 4);
  int* Mpad = (int*)alloc((size_t)NEXP * 4);
  float* xf = (float*)alloc((size_t)SEQ * DIMC * 4);
  float* wTf = (float*)alloc((size_t)DIMC * DIMC * 4);
  float* tf = (float*)alloc((size_t)SEQ * DIMC * 4);
  float* qf = (float*)alloc((size_t)SEQ * DIMC * 4);
  float* kf = (float*)alloc((size_t)SEQ * DIMC * 4);
  float* vtf = (float*)alloc((size_t)SEQ * DIMC * 4);
  float* aof = (float*)alloc((size_t)SEQ * DIMC * 4);
  u16* x_act = (u16*)alloc((size_t)SEQ * DIMC * 2);
  u16* wbuf = (u16*)alloc((size_t)HIDC * DIMC * 2);  // full-width transpose buffer
  u16* H1G = (u16*)alloc((size_t)SEQ * HIDC * 2);    // H1 -> G (in place), slot-space
  float* ff = (float*)alloc((size_t)SEQ * DIMC * 4);
  float* img = (float*)d_out;  // written by MODE2 before any read

  dim3 blk(256);
  auto gemm3 = [&](int mode, const float* A, const float* BT, int M, int N, int K, float* Cf,
                   const float* bias, const float* gv, const float* resid) {
    dim3 grid(N / 128, M / 128);
    switch (mode) {
      case 0: k_gemm3<0><<<grid, blk, 0, stream>>>(A, BT, M, N, K, Cf, bias, gv, resid); break;
      case 2: k_gemm3<2><<<grid, blk, 0, stream>>>(A, BT, M, N, K, Cf, bias, gv, resid); break;
      default: k_gemm3<6><<<grid, blk, 0, stream>>>(A, BT, M, N, K, Cf, bias, gv, resid); break;
    }
  };
  auto gemm = [&](int mode, const u16* A, const u16* BT, int M, int N, int K, float* Cf, u16* Cb,
                  const float* bias, const u16* h1) {
    dim3 grid(N / 128, M / 128);
    switch (mode) {
      case 0: k_gemm<0><<<grid, blk, 0, stream>>>(A, BT, M, N, K, Cf, Cb, bias, h1); break;
      case 1: k_gemm<1><<<grid, blk, 0, stream>>>(A, BT, M, N, K, Cf, Cb, bias, h1); break;
      case 3: k_gemm<3><<<grid, blk, 0, stream>>>(A, BT, M, N, K, Cf, Cb, bias, h1); break;
      default: k_gemm<4><<<grid, blk, 0, stream>>>(A, BT, M, N, K, Cf, Cb, bias, h1); break;
    }
  };

  // adaLN modulation vector
  k_adaln_p<<<dim3(MOD6 / 256, 16), blk, 0, stream>>>(adaln_input, W_ada, adap);
  k_adaln_r<<<dim3(MOD6 / 256), blk, 0, stream>>>(adap, b_ada, modv);

  // ---- attention branch (f32-accurate via split-bf16 GEMMs) ----
  k_ln_modf<<<dim3(SEQ), blk, 0, stream>>>(image_tokens, modv, 0, DIMC, xf);
  k_transpose_f<<<dim3(DIMC / 32, DIMC / 32), blk, 0, stream>>>(Wq, wTf, DIMC, DIMC, DIMC);
  gemm3(0, xf, wTf, SEQ, DIMC, DIMC, tf, bq, nullptr, nullptr);
  k_rms_f32<<<dim3(SEQ), blk, 0, stream>>>(tf, q_rms_w, 0.08838834764831845f, qf);
  k_transpose_f<<<dim3(DIMC / 32, DIMC / 32), blk, 0, stream>>>(Wk, wTf, DIMC, DIMC, DIMC);
  gemm3(0, xf, wTf, SEQ, DIMC, DIMC, tf, bk, nullptr, nullptr);
  k_rms_f32<<<dim3(SEQ), blk, 0, stream>>>(tf, k_rms_w, 1.f, kf);
  k_transpose_f<<<dim3(DIMC / 32, DIMC / 32), blk, 0, stream>>>(Wv, wTf, DIMC, DIMC, DIMC);
  gemm3(6, xf, wTf, SEQ, DIMC, DIMC, vtf, bv, nullptr, nullptr);
  k_flash3<<<dim3(SEQ / 64, NHEAD), blk, 0, stream>>>(qf, kf, vtf, aof);
  k_transpose_f<<<dim3(DIMC / 32, DIMC / 32), blk, 0, stream>>>(Wo, wTf, DIMC, DIMC, DIMC);
  gemm3(2, aof, wTf, SEQ, DIMC, DIMC, img, bo, modv + 2 * DIMC, image_tokens);

  // ---- MoE branch ----
  k_ln_mod<<<dim3(SEQ), blk, 0, stream>>>(img, modv, 3 * DIMC, 4 * DIMC, x_act);
  k_gate<<<dim3(SEQ), blk, 0, stream>>>(img, modv, gate_w, comb);
  k_route<<<dim3(1), blk, 0, stream>>>(comb, gidx, cw, Mpad);

  // shared expert FIRST (dense, initializes ff with a plain store)
  k_transpose<<<dim3(HSH / 32, DIMC / 32), blk, 0, stream>>>(Ws1, wbuf, DIMC, HSH, HSH);
  gemm(1, x_act, wbuf, SEQ, HSH, DIMC, nullptr, H1G, nullptr, nullptr);
  k_transpose<<<dim3(HSH / 32, DIMC / 32), blk, 0, stream>>>(Ws3, wbuf, DIMC, HSH, HSH);
  gemm(3, x_act, wbuf, SEQ, HSH, DIMC, nullptr, H1G, nullptr, H1G);
  k_transpose<<<dim3(DIMC / 32, HSH / 32), blk, 0, stream>>>(Ws2, wbuf, HSH, DIMC, DIMC);
  gemm(0, H1G, wbuf, SEQ, DIMC, HSH, ff, nullptr, nullptr, nullptr);

  // routed experts (top-2): ~half the dense FLOPs; scatter-add into ff
  for (int e = 0; e < NEXP; ++e) {
    const int* ge = gidx + e * RSTRIDE;
    const float* ce = cw + e * RSTRIDE;
    const int* me = Mpad + e;
    k_transpose<<<dim3(HIDC / 32, DIMC / 32), blk, 0, stream>>>(We1 + (size_t)e * DIMC * HIDC, wbuf,
                                                                DIMC, HIDC, HIDC);
    k_gemmR<0><<<dim3(HIDC / 128, SEQ / 128), blk, 0, stream>>>(x_act, wbuf, HIDC, DIMC, ge, ce, me,
                                                                H1G, nullptr, nullptr);
    k_transpose<<<dim3(HIDC / 32, DIMC / 32), blk, 0, stream>>>(We3 + (size_t)e * DIMC * HIDC, wbuf,
                                                                DIMC, HIDC, HIDC);
    k_gemmR<1><<<dim3(HIDC / 128, SEQ / 128), blk, 0, stream>>>(x_act, wbuf, HIDC, DIMC, ge, ce, me,
                                                                H1G, H1G, nullptr);
    k_transpose<<<dim3(DIMC / 32, HIDC / 32), blk, 0, stream>>>(We2 + (size_t)e * HIDC * DIMC, wbuf,
                                                                HIDC, DIMC, DIMC);
    k_gemmR<2><<<dim3(DIMC / 128, SEQ / 128), blk, 0, stream>>>(H1G, wbuf, DIMC, HIDC, ge, ce, me,
                                                                nullptr, nullptr, ff);
  }

  k_final<<<dim3(1024), blk, 0, stream>>>(ff, img, modv, (float*)d_out);
}

// Round 7
// 1693.696 us; speedup vs baseline: 1.6693x; 1.1186x over previous
//
#include <hip/hip_runtime.h>
#include <hip/hip_bf16.h>

typedef unsigned short u16;
typedef __bf16 bf16x8 __attribute__((ext_vector_type(8)));
typedef float f32x4 __attribute__((ext_vector_type(4)));
typedef unsigned short u16x8 __attribute__((ext_vector_type(8)));

constexpr int DIMC = 2048;
constexpr int SEQ = 2048;
constexpr int NHEAD = 16;
constexpr int HDIM = 128;
constexpr int NEXP = 4;
constexpr int HIDC = 5632;
constexpr int HSH = 2816;
constexpr int MOD6 = 6 * DIMC;
constexpr int RSTRIDE = 2304;  // per-expert routing-list stride

static __device__ __forceinline__ u16 f2bf(float f) {
  __hip_bfloat16 b = __float2bfloat16(f);
  return __builtin_bit_cast(u16, b);
}
static __device__ __forceinline__ float bf2f(u16 u) {
  unsigned int x = ((unsigned int)u) << 16;
  return __builtin_bit_cast(float, x);
}
static __device__ __forceinline__ float sigf(float x) { return 1.f / (1.f + __expf(-x)); }

static __device__ __forceinline__ void gload16(const void* src, void* dst) {
  __builtin_amdgcn_global_load_lds((const __attribute__((address_space(1))) void*)src,
                                   (__attribute__((address_space(3))) void*)dst, 16, 0, 0);
}

// split f32 8-vector (two f32x4) into hi/lo bf16x8: v ≈ h + l
static __device__ __forceinline__ void split44(f32x4 lo, f32x4 hi, bf16x8& h, bf16x8& l) {
#pragma unroll
  for (int e = 0; e < 4; ++e) {
    float f0 = lo[e];
    u16 h0 = f2bf(f0);
    h[e] = __builtin_bit_cast(__bf16, h0);
    l[e] = __builtin_bit_cast(__bf16, f2bf(f0 - bf2f(h0)));
    float f1 = hi[e];
    u16 h1 = f2bf(f1);
    h[4 + e] = __builtin_bit_cast(__bf16, h1);
    l[4 + e] = __builtin_bit_cast(__bf16, f2bf(f1 - bf2f(h1)));
  }
}

// block = 256 threads (4 waves); returns total across block to all threads
static __device__ __forceinline__ float blockSum(float v) {
#pragma unroll
  for (int m = 1; m < 64; m <<= 1) v += __shfl_xor(v, m);
  __shared__ float s[4];
  int w = threadIdx.x >> 6;
  if ((threadIdx.x & 63) == 0) s[w] = v;
  __syncthreads();
  float r = s[0] + s[1] + s[2] + s[3];
  __syncthreads();
  return r;
}

// ---------------- transpose f32 [R,C] (row stride ldin) -> bf16 [C,R]; z-batched ----------------
__global__ __launch_bounds__(256) void k_transpose(const float* __restrict__ in, u16* __restrict__ out,
                                                   int R, int C, int ldin, size_t inz, size_t outz) {
  __shared__ __align__(16) float tile[32][33];
  const float* inp = in + (size_t)blockIdx.z * inz;
  u16* outp = out + (size_t)blockIdx.z * outz;
  int tx = threadIdx.x & 31, ty = threadIdx.x >> 5;
  int c0 = blockIdx.x * 32, r0 = blockIdx.y * 32;
#pragma unroll
  for (int i = 0; i < 32; i += 8)
    tile[ty + i][tx] = inp[(size_t)(r0 + ty + i) * ldin + c0 + tx];
  __syncthreads();
#pragma unroll
  for (int i = 0; i < 32; i += 8)
    outp[(size_t)(c0 + ty + i) * R + r0 + tx] = f2bf(tile[tx][ty + i]);
}

// ---------------- transpose f32 [R,C] -> f32 [C,R] (attention weights) ----------------
__global__ __launch_bounds__(256) void k_transpose_f(const float* __restrict__ in, float* __restrict__ out,
                                                     int R, int C, int ldin) {
  __shared__ __align__(16) float tile[32][33];
  int tx = threadIdx.x & 31, ty = threadIdx.x >> 5;
  int c0 = blockIdx.x * 32, r0 = blockIdx.y * 32;
#pragma unroll
  for (int i = 0; i < 32; i += 8)
    tile[ty + i][tx] = in[(size_t)(r0 + ty + i) * ldin + c0 + tx];
  __syncthreads();
#pragma unroll
  for (int i = 0; i < 32; i += 8)
    out[(size_t)(c0 + ty + i) * R + r0 + tx] = tile[tx][ty + i];
}

// ---------------- adaLN: mod = silu(a) @ W_ada + b_ada, split over 16 d-slices ----------------
__global__ __launch_bounds__(256) void k_adaln_p(const float* __restrict__ a, const float* __restrict__ W,
                                                 float* __restrict__ partial) {
  __shared__ float sa[128];
  int tid = threadIdx.x, slice = blockIdx.y;
  if (tid < 128) { float v = a[slice * 128 + tid]; sa[tid] = v * sigf(v); }
  __syncthreads();
  int j = blockIdx.x * 256 + tid;
  float acc = 0.f;
#pragma unroll 4
  for (int d = 0; d < 128; ++d) acc += sa[d] * W[(size_t)(slice * 128 + d) * MOD6 + j];
  partial[(size_t)slice * MOD6 + j] = acc;
}
__global__ __launch_bounds__(256) void k_adaln_r(const float* __restrict__ partial, const float* __restrict__ b,
                                                 float* __restrict__ mod) {
  int j = blockIdx.x * 256 + threadIdx.x;
  float acc = b[j];
#pragma unroll
  for (int s = 0; s < 16; ++s) acc += partial[(size_t)s * MOD6 + j];
  mod[j] = acc;
}

// ---------------- LayerNorm + adaLN modulate -> f32 (attention x) ----------------
__global__ __launch_bounds__(256) void k_ln_modf(const float* __restrict__ X, const float* __restrict__ mod,
                                                 int shOff, int scOff, float* __restrict__ out) {
  int row = blockIdx.x, tid = threadIdx.x;
  const float4* x4 = (const float4*)(X + (size_t)row * DIMC);
  float4 v0 = x4[tid * 2], v1 = x4[tid * 2 + 1];
  float s = v0.x + v0.y + v0.z + v0.w + v1.x + v1.y + v1.z + v1.w;
  float ss = v0.x * v0.x + v0.y * v0.y + v0.z * v0.z + v0.w * v0.w +
             v1.x * v1.x + v1.y * v1.y + v1.z * v1.z + v1.w * v1.w;
  s = blockSum(s);
  ss = blockSum(ss);
  float mean = s * (1.f / DIMC);
  float var = ss * (1.f / DIMC) - mean * mean;
  float rstd = rsqrtf(var + 1e-6f);
  const float* sh = mod + shOff;
  const float* sc = mod + scOff;
  int c = tid * 8;
  float xv[8] = {v0.x, v0.y, v0.z, v0.w, v1.x, v1.y, v1.z, v1.w};
  float ov[8];
#pragma unroll
  for (int e = 0; e < 8; ++e) ov[e] = (xv[e] - mean) * rstd * (1.f + sc[c + e]) + sh[c + e];
  float4 o0 = {ov[0], ov[1], ov[2], ov[3]}, o1 = {ov[4], ov[5], ov[6], ov[7]};
  float4* y4 = (float4*)(out + (size_t)row * DIMC);
  y4[tid * 2] = o0;
  y4[tid * 2 + 1] = o1;
}

// ---------------- LayerNorm + adaLN modulate -> bf16 (MoE x_act) ----------------
__global__ __launch_bounds__(256) void k_ln_mod(const float* __restrict__ X, const float* __restrict__ mod,
                                                int shOff, int scOff, u16* __restrict__ out) {
  int row = blockIdx.x, tid = threadIdx.x;
  const float4* x4 = (const float4*)(X + (size_t)row * DIMC);
  float4 v0 = x4[tid * 2], v1 = x4[tid * 2 + 1];
  float s = v0.x + v0.y + v0.z + v0.w + v1.x + v1.y + v1.z + v1.w;
  float ss = v0.x * v0.x + v0.y * v0.y + v0.z * v0.z + v0.w * v0.w +
             v1.x * v1.x + v1.y * v1.y + v1.z * v1.z + v1.w * v1.w;
  s = blockSum(s);
  ss = blockSum(ss);
  float mean = s * (1.f / DIMC);
  float var = ss * (1.f / DIMC) - mean * mean;
  float rstd = rsqrtf(var + 1e-6f);
  const float* sh = mod + shOff;
  const float* sc = mod + scOff;
  int c = tid * 8;
  float xv[8] = {v0.x, v0.y, v0.z, v0.w, v1.x, v1.y, v1.z, v1.w};
  u16x8 o;
#pragma unroll
  for (int e = 0; e < 8; ++e) o[e] = f2bf((xv[e] - mean) * rstd * (1.f + sc[c + e]) + sh[c + e]);
  *(u16x8*)(out + (size_t)row * DIMC + c) = o;
}

// ---------------- RMSNorm f32 in -> f32 out, * weight * scale ----------------
__global__ __launch_bounds__(256) void k_rms_f32(const float* __restrict__ X, const float* __restrict__ w,
                                                 float scale, float* __restrict__ out) {
  int row = blockIdx.x, tid = threadIdx.x;
  const float4* x4 = (const float4*)(X + (size_t)row * DIMC);
  float4 v0 = x4[tid * 2], v1 = x4[tid * 2 + 1];
  float ss = v0.x * v0.x + v0.y * v0.y + v0.z * v0.z + v0.w * v0.w +
             v1.x * v1.x + v1.y * v1.y + v1.z * v1.z + v1.w * v1.w;
  ss = blockSum(ss);
  float rstd = rsqrtf(ss * (1.f / DIMC) + 1e-5f) * scale;
  int c = tid * 8;
  float xv[8] = {v0.x, v0.y, v0.z, v0.w, v1.x, v1.y, v1.z, v1.w};
  float ov[8];
#pragma unroll
  for (int e = 0; e < 8; ++e) ov[e] = xv[e] * rstd * w[c + e];
  float4 o0 = {ov[0], ov[1], ov[2], ov[3]}, o1 = {ov[4], ov[5], ov[6], ov[7]};
  float4* y4 = (float4*)(out + (size_t)row * DIMC);
  y4[tid * 2] = o0;
  y4[tid * 2 + 1] = o1;
}

// ---------------- gating: recompute LN+mod in f32, softmax over 4, top-2 -> comb[n][4] ----------------
__global__ __launch_bounds__(256) void k_gate(const float* __restrict__ img, const float* __restrict__ mod,
                                              const float* __restrict__ gw, float* __restrict__ comb) {
  int n = blockIdx.x, tid = threadIdx.x;
  const float4* x4 = (const float4*)(img + (size_t)n * DIMC);
  float4 v0 = x4[tid * 2], v1 = x4[tid * 2 + 1];
  float s = v0.x + v0.y + v0.z + v0.w + v1.x + v1.y + v1.z + v1.w;
  float ss = v0.x * v0.x + v0.y * v0.y + v0.z * v0.z + v0.w * v0.w +
             v1.x * v1.x + v1.y * v1.y + v1.z * v1.z + v1.w * v1.w;
  s = blockSum(s);
  ss = blockSum(ss);
  float mean = s * (1.f / DIMC);
  float var = ss * (1.f / DIMC) - mean * mean;
  float rstd = rsqrtf(var + 1e-6f);
  const float* sh = mod + 3 * DIMC;
  const float* sc = mod + 4 * DIMC;
  int c = tid * 8;
  float xv[8] = {v0.x, v0.y, v0.z, v0.w, v1.x, v1.y, v1.z, v1.w};
  float y[8];
#pragma unroll
  for (int e = 0; e < 8; ++e) y[e] = (xv[e] - mean) * rstd * (1.f + sc[c + e]) + sh[c + e];
  float accs[NEXP];
#pragma unroll
  for (int ex = 0; ex < NEXP; ++ex) {
    float a = 0.f;
#pragma unroll
    for (int e = 0; e < 8; ++e) a += y[e] * gw[(size_t)ex * DIMC + c + e];
    accs[ex] = blockSum(a);
  }
  if (tid == 0) {
    float mx = fmaxf(fmaxf(accs[0], accs[1]), fmaxf(accs[2], accs[3]));
    float ex0 = __expf(accs[0] - mx), ex1 = __expf(accs[1] - mx);
    float ex2 = __expf(accs[2] - mx), ex3 = __expf(accs[3] - mx);
    float inv = 1.f / (ex0 + ex1 + ex2 + ex3);
    float v[4] = {ex0 * inv, ex1 * inv, ex2 * inv, ex3 * inv};
    int i1 = 0;
    for (int e = 1; e < 4; ++e)
      if (v[e] > v[i1]) i1 = e;
    int i2 = -1;
    for (int e = 0; e < 4; ++e) {
      if (e == i1) continue;
      if (i2 < 0 || v[e] > v[i2]) i2 = e;
    }
    for (int e = 0; e < 4; ++e) comb[(size_t)n * 4 + e] = (e == i1 || e == i2) ? v[e] : 0.f;
  }
}

// ---------------- routing: deterministic per-expert token lists (1 block, wave e = expert e) ----------------
__global__ __launch_bounds__(256) void k_route(const float* __restrict__ comb, int* __restrict__ gidx,
                                               float* __restrict__ cw, int* __restrict__ Mpad) {
  int wid = threadIdx.x >> 6, lane = threadIdx.x & 63;
  int base = 0;
  for (int c = 0; c < SEQ; c += 64) {
    int n = c + lane;
    float w = comb[(size_t)n * NEXP + wid];
    bool sel = w > 0.f;
    unsigned long long mask = __ballot(sel);
    int pos = __popcll(mask & ((1ull << lane) - 1ull));
    if (sel) {
      gidx[wid * RSTRIDE + base + pos] = n;
      cw[wid * RSTRIDE + base + pos] = w;
    }
    base += __popcll(mask);
  }
  int padded = (base + 127) & ~127;
  for (int i = base + lane; i < padded; i += 64) {
    gidx[wid * RSTRIDE + i] = -1;
    cw[wid * RSTRIDE + i] = 0.f;
  }
  if (lane == 0) Mpad[wid] = padded;
}

// ---------------- bf16 GEMM (dense, shared expert): C[M,N] = A @ BT^T; BK=64 dual-buffer ----------------
// MODE 0: Cf = acc   1: Cb = bf16(acc)   3: Cb = bf16(silu(h1)*acc)
template <int MODE>
__global__ __launch_bounds__(256, 2) void k_gemm(const u16* __restrict__ A, const u16* __restrict__ BT,
                                                 int M, int N, int K, float* __restrict__ Cf,
                                                 u16* __restrict__ Cb, const u16* __restrict__ h1) {
  __shared__ __align__(16) u16 AsA[4096], AsB[4096], BsA[4096], BsB[4096];
  const int tid = threadIdx.x, wid = tid >> 6, lane = tid & 63;
  const int l16 = lane & 15, g = lane >> 4;
  const int wr = wid >> 1, wc = wid & 1;
  const int m0 = blockIdx.y * 128, n0 = blockIdx.x * 128;
  const int srow = lane >> 2, scol = (lane & 3) * 8;
  const u16* aS0 = A + (size_t)(m0 + wid * 32 + srow) * K + scol;
  const u16* aS1 = aS0 + (size_t)16 * K;
  const u16* bS0 = BT + (size_t)(n0 + wid * 32 + srow) * K + scol;
  const u16* bS1 = bS0 + (size_t)16 * K;
  u16* aDA0 = &AsA[wid * 1024];
  u16* aDA1 = aDA0 + 512;
  u16* bDA0 = &BsA[wid * 1024];
  u16* bDA1 = bDA0 + 512;
  u16* aDB0 = &AsB[wid * 1024];
  u16* aDB1 = aDB0 + 512;
  u16* bDB0 = &BsB[wid * 1024];
  u16* bDB1 = bDB0 + 512;

  const f32x4 zero4 = {0.f, 0.f, 0.f, 0.f};
  f32x4 acc[4][4];
#pragma unroll
  for (int mi = 0; mi < 4; ++mi)
#pragma unroll
    for (int ni = 0; ni < 4; ++ni) acc[mi][ni] = zero4;

  for (int k0 = 0; k0 < K; k0 += 64) {
    __syncthreads();
    gload16(aS0 + k0, aDA0);
    gload16(aS1 + k0, aDA1);
    gload16(bS0 + k0, bDA0);
    gload16(bS1 + k0, bDA1);
    gload16(aS0 + k0 + 32, aDB0);
    gload16(aS1 + k0 + 32, aDB1);
    gload16(bS0 + k0 + 32, bDB0);
    gload16(bS1 + k0 + 32, bDB1);
    __syncthreads();
#pragma unroll
    for (int hh = 0; hh < 2; ++hh) {
      const u16* Asrc = hh ? AsB : AsA;
      const u16* Bsrc = hh ? BsB : BsA;
      bf16x8 af[4], bfr[4];
#pragma unroll
      for (int mi = 0; mi < 4; ++mi)
        af[mi] = *(const bf16x8*)(&Asrc[(wr * 64 + mi * 16 + l16) * 32 + g * 8]);
#pragma unroll
      for (int ni = 0; ni < 4; ++ni)
        bfr[ni] = *(const bf16x8*)(&Bsrc[(wc * 64 + ni * 16 + l16) * 32 + g * 8]);
#pragma unroll
      for (int mi = 0; mi < 4; ++mi)
#pragma unroll
        for (int ni = 0; ni < 4; ++ni)
          acc[mi][ni] = __builtin_amdgcn_mfma_f32_16x16x32_bf16(af[mi], bfr[ni], acc[mi][ni], 0, 0, 0);
    }
  }

#pragma unroll
  for (int mi = 0; mi < 4; ++mi) {
#pragma unroll
    for (int ni = 0; ni < 4; ++ni) {
      const int col = n0 + wc * 64 + ni * 16 + l16;
#pragma unroll
      for (int r = 0; r < 4; ++r) {
        const int row = m0 + wr * 64 + mi * 16 + g * 4 + r;
        const size_t idx = (size_t)row * N + col;
        float v = acc[mi][ni][r];
        if constexpr (MODE == 0) {
          Cf[idx] = v;
        } else if constexpr (MODE == 1) {
          Cb[idx] = f2bf(v);
        } else {
          float hv = bf2f(h1[idx]);
          float sw = hv * sigf(hv);
          Cb[idx] = f2bf(sw * v);
        }
      }
    }
  }
}

// ---------------- routed bf16 GEMM (experts); BK=64 dual-buffer; z = expert within batch ----------------
// RM 0: H1[slot][col] = bf16(acc)                        A-rows gathered via gidxE
// RM 1: G[slot][col]  = bf16(silu(h1)*acc*cwE[slot])     A-rows gathered via gidxE
// RM 2: t=gidxE[slot]; if(t>=0) ff[t*N+col] += acc       A linear (slot space)
template <int RM>
__global__ __launch_bounds__(256, 2) void k_gemmR(const u16* __restrict__ A0, size_t az,
                                                  const u16* __restrict__ BT0, size_t bz, int N, int K,
                                                  const int* __restrict__ gidx0,
                                                  const float* __restrict__ cw0,
                                                  const int* __restrict__ Mp0, u16* __restrict__ Cb0,
                                                  size_t cz, const u16* __restrict__ h10,
                                                  float* __restrict__ ff) {
  const int z = blockIdx.z;
  const int* gidxE = gidx0 + (size_t)z * RSTRIDE;
  const int m0 = blockIdx.y * 128;
  if (m0 >= Mp0[z]) return;  // data-dependent early exit (Mpad multiple of 128)
  const float* cwE = cw0 + (size_t)z * RSTRIDE;
  const u16* A = A0 + (size_t)z * az;
  const u16* BT = BT0 + (size_t)z * bz;
  u16* Cb = Cb0 + (size_t)z * cz;
  const u16* h1 = h10 + (size_t)z * cz;

  __shared__ __align__(16) u16 AsA[4096], AsB[4096], BsA[4096], BsB[4096];
  const int tid = threadIdx.x, wid = tid >> 6, lane = tid & 63;
  const int l16 = lane & 15, g = lane >> 4;
  const int wr = wid >> 1, wc = wid & 1;
  const int n0 = blockIdx.x * 128;
  const int srow = lane >> 2, scol = (lane & 3) * 8;
  const int slot0 = m0 + wid * 32 + srow;
  int row0, row1;
  if constexpr (RM == 2) {
    row0 = slot0;
    row1 = slot0 + 16;
  } else {
    int t0 = gidxE[slot0], t1 = gidxE[slot0 + 16];
    row0 = t0 < 0 ? 0 : t0;  // pad slots read token 0; masked by cw=0 / store-skip
    row1 = t1 < 0 ? 0 : t1;
  }
  const u16* aS0 = A + (size_t)row0 * K + scol;
  const u16* aS1 = A + (size_t)row1 * K + scol;
  const u16* bS0 = BT + (size_t)(n0 + wid * 32 + srow) * K + scol;
  const u16* bS1 = bS0 + (size_t)16 * K;
  u16* aDA0 = &AsA[wid * 1024];
  u16* aDA1 = aDA0 + 512;
  u16* bDA0 = &BsA[wid * 1024];
  u16* bDA1 = bDA0 + 512;
  u16* aDB0 = &AsB[wid * 1024];
  u16* aDB1 = aDB0 + 512;
  u16* bDB0 = &BsB[wid * 1024];
  u16* bDB1 = bDB0 + 512;

  const f32x4 zero4 = {0.f, 0.f, 0.f, 0.f};
  f32x4 acc[4][4];
#pragma unroll
  for (int mi = 0; mi < 4; ++mi)
#pragma unroll
    for (int ni = 0; ni < 4; ++ni) acc[mi][ni] = zero4;

  for (int k0 = 0; k0 < K; k0 += 64) {
    __syncthreads();
    gload16(aS0 + k0, aDA0);
    gload16(aS1 + k0, aDA1);
    gload16(bS0 + k0, bDA0);
    gload16(bS1 + k0, bDA1);
    gload16(aS0 + k0 + 32, aDB0);
    gload16(aS1 + k0 + 32, aDB1);
    gload16(bS0 + k0 + 32, bDB0);
    gload16(bS1 + k0 + 32, bDB1);
    __syncthreads();
#pragma unroll
    for (int hh = 0; hh < 2; ++hh) {
      const u16* Asrc = hh ? AsB : AsA;
      const u16* Bsrc = hh ? BsB : BsA;
      bf16x8 af[4], bfr[4];
#pragma unroll
      for (int mi = 0; mi < 4; ++mi)
        af[mi] = *(const bf16x8*)(&Asrc[(wr * 64 + mi * 16 + l16) * 32 + g * 8]);
#pragma unroll
      for (int ni = 0; ni < 4; ++ni)
        bfr[ni] = *(const bf16x8*)(&Bsrc[(wc * 64 + ni * 16 + l16) * 32 + g * 8]);
#pragma unroll
      for (int mi = 0; mi < 4; ++mi)
#pragma unroll
        for (int ni = 0; ni < 4; ++ni)
          acc[mi][ni] = __builtin_amdgcn_mfma_f32_16x16x32_bf16(af[mi], bfr[ni], acc[mi][ni], 0, 0, 0);
    }
  }

#pragma unroll
  for (int mi = 0; mi < 4; ++mi) {
#pragma unroll
    for (int ni = 0; ni < 4; ++ni) {
      const int col = n0 + wc * 64 + ni * 16 + l16;
#pragma unroll
      for (int r = 0; r < 4; ++r) {
        const int slot = m0 + wr * 64 + mi * 16 + g * 4 + r;
        const size_t idx = (size_t)slot * N + col;
        float v = acc[mi][ni][r];
        if constexpr (RM == 0) {
          Cb[idx] = f2bf(v);
        } else if constexpr (RM == 1) {
          float hv = bf2f(h1[idx]);
          float sw = hv * sigf(hv);
          Cb[idx] = f2bf(sw * v * cwE[slot]);
        } else {
          int t = gidxE[slot];
          if (t >= 0) ff[(size_t)t * N + col] += v;
        }
      }
    }
  }
}

// ---------------- split-precision GEMM: reg-stage + pre-split hi/lo LDS, stride-80 rows ----------------
// MODE 0: Cf = acc+bias
// MODE 2: Cf = (acc+bias)*gvec[col] + resid
// MODE 6: Cf[col*M+row] = acc+bias   (transposed f32 store, for V^T)
template <int MODE>
__global__ __launch_bounds__(256, 2) void k_gemm3(const float* __restrict__ A, const float* __restrict__ BT,
                                                  int M, int N, int K, float* __restrict__ Cf,
                                                  const float* __restrict__ bias,
                                                  const float* __restrict__ gvec,
                                                  const float* __restrict__ resid) {
  __shared__ __align__(16) u16 Ah[128 * 40], Al[128 * 40], Bh[128 * 40], Bl[128 * 40];
  const int tid = threadIdx.x, wid = tid >> 6, lane = tid & 63;
  const int l16 = lane & 15, g = lane >> 4;
  const int wr = wid >> 1, wc = wid & 1;
  const int m0 = blockIdx.y * 128, n0 = blockIdx.x * 128;

  const int srow = tid >> 1, se0 = (tid & 1) * 16;
  char* ahp = (char*)Ah + srow * 80 + se0 * 2;
  char* alp = (char*)Al + srow * 80 + se0 * 2;
  char* bhp = (char*)Bh + srow * 80 + se0 * 2;
  char* blp = (char*)Bl + srow * 80 + se0 * 2;
  const float* aS = A + (size_t)(m0 + srow) * K + se0;
  const float* bS = BT + (size_t)(n0 + srow) * K + se0;

  f32x4 ar[4], br[4];
#pragma unroll
  for (int c = 0; c < 4; ++c) {
    ar[c] = *(const f32x4*)(aS + c * 4);
    br[c] = *(const f32x4*)(bS + c * 4);
  }

  const f32x4 zero4 = {0.f, 0.f, 0.f, 0.f};
  f32x4 acc[4][4];
#pragma unroll
  for (int mi = 0; mi < 4; ++mi)
#pragma unroll
    for (int ni = 0; ni < 4; ++ni) acc[mi][ni] = zero4;

  for (int k0 = 0; k0 < K; k0 += 32) {
    __syncthreads();
    bf16x8 h0, l0, h1, l1;
    split44(ar[0], ar[1], h0, l0);
    split44(ar[2], ar[3], h1, l1);
    *(bf16x8*)(ahp) = h0;
    *(bf16x8*)(ahp + 16) = h1;
    *(bf16x8*)(alp) = l0;
    *(bf16x8*)(alp + 16) = l1;
    split44(br[0], br[1], h0, l0);
    split44(br[2], br[3], h1, l1);
    *(bf16x8*)(bhp) = h0;
    *(bf16x8*)(bhp + 16) = h1;
    *(bf16x8*)(blp) = l0;
    *(bf16x8*)(blp + 16) = l1;
    __syncthreads();
    if (k0 + 32 < K) {  // T14: issue next tile's loads under the MFMAs
#pragma unroll
      for (int c = 0; c < 4; ++c) {
        ar[c] = *(const f32x4*)(aS + k0 + 32 + c * 4);
        br[c] = *(const f32x4*)(bS + k0 + 32 + c * 4);
      }
    }
    bf16x8 bhf[4], blf[4];
#pragma unroll
    for (int ni = 0; ni < 4; ++ni) {
      const int rb = wc * 64 + ni * 16 + l16;
      bhf[ni] = *(const bf16x8*)((char*)Bh + rb * 80 + g * 16);
      blf[ni] = *(const bf16x8*)((char*)Bl + rb * 80 + g * 16);
    }
#pragma unroll
    for (int mi = 0; mi < 4; ++mi) {
      const int ra = wr * 64 + mi * 16 + l16;
      bf16x8 ahf = *(const bf16x8*)((char*)Ah + ra * 80 + g * 16);
      bf16x8 alf = *(const bf16x8*)((char*)Al + ra * 80 + g * 16);
#pragma unroll
      for (int ni = 0; ni < 4; ++ni) {
        acc[mi][ni] = __builtin_amdgcn_mfma_f32_16x16x32_bf16(alf, bhf[ni], acc[mi][ni], 0, 0, 0);
        acc[mi][ni] = __builtin_amdgcn_mfma_f32_16x16x32_bf16(ahf, blf[ni], acc[mi][ni], 0, 0, 0);
        acc[mi][ni] = __builtin_amdgcn_mfma_f32_16x16x32_bf16(ahf, bhf[ni], acc[mi][ni], 0, 0, 0);
      }
    }
  }

#pragma unroll
  for (int mi = 0; mi < 4; ++mi) {
#pragma unroll
    for (int ni = 0; ni < 4; ++ni) {
      const int col = n0 + wc * 64 + ni * 16 + l16;
      float bv = bias ? bias[col] : 0.f;
#pragma unroll
      for (int r = 0; r < 4; ++r) {
        const int row = m0 + wr * 64 + mi * 16 + g * 4 + r;
        float v = acc[mi][ni][r] + bv;
        if constexpr (MODE == 0) {
          Cf[(size_t)row * N + col] = v;
        } else if constexpr (MODE == 2) {
          Cf[(size_t)row * N + col] = v * gvec[col] + resid[(size_t)row * N + col];
        } else {
          Cf[(size_t)col * M + row] = v;
        }
      }
    }
  }
}

// ---------------- flash attention: block-staged pre-split K/V in LDS (UNCHANGED from R6) ----------------
__global__ __launch_bounds__(256, 2) void k_flash3(const float* __restrict__ q, const float* __restrict__ kk,
                                                   const float* __restrict__ vt, float* __restrict__ o) {
  __shared__ __align__(16) u16 Kh[4096], Kl[4096], Vh[128 * 40], Vl[128 * 40];
  __shared__ __align__(16) u16 Pah[4][16 * 40], Pal[4][16 * 40];
  const int tid = threadIdx.x, wid = tid >> 6, lane = tid & 63;
  const int l16 = lane & 15, g = lane >> 4;
  const int h = blockIdx.y;
  const int r0 = blockIdx.x * 64 + wid * 16;
  const size_t hOff = (size_t)h * HDIM;

  bf16x8 qh[4], ql[4];
#pragma unroll
  for (int kc = 0; kc < 4; ++kc) {
    const float* qp = q + (size_t)(r0 + l16) * DIMC + hOff + kc * 32 + g * 8;
    split44(*(const f32x4*)qp, *(const f32x4*)(qp + 4), qh[kc], ql[kc]);
  }

  const int kr = tid >> 3, ke0 = (tid & 7) * 16;
  const int kswz = (kr & 7) << 4;
  const int kc0 = (ke0 * 2) ^ kswz, kc1 = (ke0 * 2 + 16) ^ kswz;
  char* khp = (char*)Kh + kr * 256;
  char* klp = (char*)Kl + kr * 256;
  const float* kBase = kk + (size_t)kr * DIMC + hOff + ke0;
  const int vr = tid >> 1, ve0 = (tid & 1) * 16;
  char* vhp = (char*)Vh + vr * 80 + ve0 * 2;
  char* vlp = (char*)Vl + vr * 80 + ve0 * 2;
  const float* vBase = vt + (size_t)(hOff + vr) * SEQ + ve0;

  f32x4 kReg[4], vReg[4];
#pragma unroll
  for (int c = 0; c < 4; ++c) {
    kReg[c] = *(const f32x4*)(kBase + c * 4);
    vReg[c] = *(const f32x4*)(vBase + c * 4);
  }

  const f32x4 zero4 = {0.f, 0.f, 0.f, 0.f};
  f32x4 oacc[8];
#pragma unroll
  for (int db = 0; db < 8; ++db) oacc[db] = zero4;
  float mr[4], lr[4];
#pragma unroll
  for (int r = 0; r < 4; ++r) {
    mr[r] = -3.0e38f;
    lr[r] = 0.f;
  }

  for (int j0 = 0; j0 < SEQ; j0 += 32) {
    __syncthreads();
    bf16x8 h0, l0, h1, l1;
    split44(kReg[0], kReg[1], h0, l0);
    split44(kReg[2], kReg[3], h1, l1);
    *(bf16x8*)(khp + kc0) = h0;
    *(bf16x8*)(khp + kc1) = h1;
    *(bf16x8*)(klp + kc0) = l0;
    *(bf16x8*)(klp + kc1) = l1;
    split44(vReg[0], vReg[1], h0, l0);
    split44(vReg[2], vReg[3], h1, l1);
    *(bf16x8*)(vhp) = h0;
    *(bf16x8*)(vhp + 16) = h1;
    *(bf16x8*)(vlp) = l0;
    *(bf16x8*)(vlp + 16) = l1;
    __syncthreads();
    if (j0 + 32 < SEQ) {
      const float* kp = kBase + (size_t)(j0 + 32) * DIMC;
      const float* vp = vBase + j0 + 32;
#pragma unroll
      for (int c = 0; c < 4; ++c) {
        kReg[c] = *(const f32x4*)(kp + c * 4);
        vReg[c] = *(const f32x4*)(vp + c * 4);
      }
    }
    f32x4 s0 = zero4, s1 = zero4;
    __builtin_amdgcn_s_setprio(1);
#pragma unroll
    for (int kc = 0; kc < 4; ++kc) {
      const int cb = (kc * 64 + g * 16) ^ ((l16 & 7) << 4);
      bf16x8 kh0 = *(const bf16x8*)((char*)Kh + l16 * 256 + cb);
      bf16x8 kl0 = *(const bf16x8*)((char*)Kl + l16 * 256 + cb);
      bf16x8 kh1 = *(const bf16x8*)((char*)Kh + (16 + l16) * 256 + cb);
      bf16x8 kl1 = *(const bf16x8*)((char*)Kl + (16 + l16) * 256 + cb);
      s0 = __builtin_amdgcn_mfma_f32_16x16x32_bf16(ql[kc], kh0, s0, 0, 0, 0);
      s0 = __builtin_amdgcn_mfma_f32_16x16x32_bf16(qh[kc], kl0, s0, 0, 0, 0);
      s0 = __builtin_amdgcn_mfma_f32_16x16x32_bf16(qh[kc], kh0, s0, 0, 0, 0);
      s1 = __builtin_amdgcn_mfma_f32_16x16x32_bf16(ql[kc], kh1, s1, 0, 0, 0);
      s1 = __builtin_amdgcn_mfma_f32_16x16x32_bf16(qh[kc], kl1, s1, 0, 0, 0);
      s1 = __builtin_amdgcn_mfma_f32_16x16x32_bf16(qh[kc], kh1, s1, 0, 0, 0);
    }
    __builtin_amdgcn_s_setprio(0);
    float corr[4];
#pragma unroll
    for (int r = 0; r < 4; ++r) {
      float tm = fmaxf(s0[r], s1[r]);
#pragma unroll
      for (int m = 1; m < 16; m <<= 1) tm = fmaxf(tm, __shfl_xor(tm, m));
      float mn = fmaxf(mr[r], tm);
      corr[r] = __expf(mr[r] - mn);
      mr[r] = mn;
      float p0 = __expf(s0[r] - mn);
      float p1 = __expf(s1[r] - mn);
      lr[r] = lr[r] * corr[r] + p0 + p1;
      u16 p0h = f2bf(p0), p1h = f2bf(p1);
      Pah[wid][(g * 4 + r) * 40 + l16] = p0h;
      Pah[wid][(g * 4 + r) * 40 + 16 + l16] = p1h;
      Pal[wid][(g * 4 + r) * 40 + l16] = f2bf(p0 - bf2f(p0h));
      Pal[wid][(g * 4 + r) * 40 + 16 + l16] = f2bf(p1 - bf2f(p1h));
    }
#pragma unroll
    for (int db = 0; db < 8; ++db)
#pragma unroll
      for (int r = 0; r < 4; ++r) oacc[db][r] *= corr[r];
    bf16x8 pfh = *(const bf16x8*)(&Pah[wid][l16 * 40 + g * 8]);
    bf16x8 pfl = *(const bf16x8*)(&Pal[wid][l16 * 40 + g * 8]);
    __builtin_amdgcn_s_setprio(1);
#pragma unroll
    for (int db = 0; db < 8; ++db) {
      const int row = db * 16 + l16;
      bf16x8 vh = *(const bf16x8*)((char*)Vh + row * 80 + g * 16);
      bf16x8 vl = *(const bf16x8*)((char*)Vl + row * 80 + g * 16);
      oacc[db] = __builtin_amdgcn_mfma_f32_16x16x32_bf16(pfl, vh, oacc[db], 0, 0, 0);
      oacc[db] = __builtin_amdgcn_mfma_f32_16x16x32_bf16(pfh, vl, oacc[db], 0, 0, 0);
      oacc[db] = __builtin_amdgcn_mfma_f32_16x16x32_bf16(pfh, vh, oacc[db], 0, 0, 0);
    }
    __builtin_amdgcn_s_setprio(0);
  }
#pragma unroll
  for (int r = 0; r < 4; ++r) {
#pragma unroll
    for (int m = 1; m < 16; m <<= 1) lr[r] += __shfl_xor(lr[r], m);
    lr[r] = 1.f / lr[r];
  }
#pragma unroll
  for (int db = 0; db < 8; ++db)
#pragma unroll
    for (int r = 0; r < 4; ++r)
      o[(size_t)(r0 + g * 4 + r) * DIMC + hOff + db * 16 + l16] = oacc[db][r] * lr[r];
}

// ---------------- final: out = g_mlp[col]*ff + img   (img aliases out; in-place) ----------------
__global__ __launch_bounds__(256) void k_final(const float* __restrict__ ff, const float* img,
                                               const float* __restrict__ mod, float* out) {
  const float4* gm = (const float4*)(mod + 5 * DIMC);
  const int total = SEQ * DIMC / 4;
  const int stride = gridDim.x * blockDim.x;
  for (int i = blockIdx.x * blockDim.x + threadIdx.x; i < total; i += stride) {
    int col4 = i & (DIMC / 4 - 1);
    float4 gv = gm[col4];
    float4 fv = ((const float4*)ff)[i];
    float4 iv = ((const float4*)img)[i];
    float4 ov;
    ov.x = gv.x * fv.x + iv.x;
    ov.y = gv.y * fv.y + iv.y;
    ov.z = gv.z * fv.z + iv.z;
    ov.w = gv.w * fv.w + iv.w;
    ((float4*)out)[i] = ov;
  }
}

extern "C" void kernel_launch(void* const* d_in, const int* in_sizes, int n_in, void* d_out, int out_size,
                              void* d_ws, size_t ws_size, hipStream_t stream) {
  (void)in_sizes; (void)n_in; (void)out_size; (void)ws_size;
  const float* image_tokens = (const float*)d_in[0];
  const float* adaln_input = (const float*)d_in[1];
  const float* W_ada = (const float*)d_in[2];
  const float* b_ada = (const float*)d_in[3];
  const float* Wq = (const float*)d_in[4];
  const float* bq = (const float*)d_in[5];
  const float* Wk = (const float*)d_in[6];
  const float* bk = (const float*)d_in[7];
  const float* Wv = (const float*)d_in[8];
  const float* bv = (const float*)d_in[9];
  const float* q_rms_w = (const float*)d_in[10];
  const float* k_rms_w = (const float*)d_in[11];
  const float* Wo = (const float*)d_in[12];
  const float* bo = (const float*)d_in[13];
  const float* gate_w = (const float*)d_in[14];
  const float* We1 = (const float*)d_in[15];
  const float* We3 = (const float*)d_in[16];
  const float* We2 = (const float*)d_in[17];
  const float* Ws1 = (const float*)d_in[18];
  const float* Ws3 = (const float*)d_in[19];
  const float* Ws2 = (const float*)d_in[20];

  // ---- workspace: ~144 MB (MoE batching buffers alias the dead attention-phase region) ----
  char* cur = (char*)d_ws;
  auto alloc = [&](size_t n) {
    char* p = cur;
    cur += (n + 255) & ~(size_t)255;
    return p;
  };
  float* modv = (float*)alloc((size_t)MOD6 * 4);
  float* adap = (float*)alloc((size_t)16 * MOD6 * 4);
  float* comb = (float*)alloc((size_t)SEQ * NEXP * 4);
  int* gidx = (int*)alloc((size_t)NEXP * RSTRIDE * 4);
  float* cw = (float*)alloc((size_t)NEXP * RSTRIDE * 4);
  int* Mpad = (int*)alloc((size_t)NEXP * 4);
  float* xf = (float*)alloc((size_t)SEQ * DIMC * 4);    // start of 7x16.78MB attention region
  float* wTf = (float*)alloc((size_t)DIMC * DIMC * 4);
  float* tf = (float*)alloc((size_t)SEQ * DIMC * 4);
  float* qf = (float*)alloc((size_t)SEQ * DIMC * 4);
  float* kf = (float*)alloc((size_t)SEQ * DIMC * 4);
  float* vtf = (float*)alloc((size_t)SEQ * DIMC * 4);
  float* aof = (float*)alloc((size_t)SEQ * DIMC * 4);
  u16* x_act = (u16*)alloc((size_t)SEQ * DIMC * 2);
  float* ff = (float*)alloc((size_t)SEQ * DIMC * 4);
  float* img = (float*)d_out;  // written by MODE2 before any read
  // MoE-phase aliases into the dead attention region (xf..aof = 117.4MB):
  //   wbufE: 2 experts' transposed weights, 2x23.07MB = 46.14MB
  //   H1G2 : 2 experts' slot-space H1/G,    2x25.95MB = 51.90MB   (total 98.0MB <= 117.4MB)
  u16* wbufE = (u16*)xf;
  u16* H1G2 = (u16*)((char*)xf + (size_t)2 * HIDC * DIMC * 2);
  const size_t BZ = (size_t)HIDC * DIMC;    // wbufE per-z stride (elements)
  const size_t CZ = (size_t)RSTRIDE * HIDC; // H1G2 per-z stride (elements)
  u16* wbufS = wbufE;  // shared-expert transpose buffer (11.5MB, disjoint from H1G2)
  u16* H1Gs = H1G2;    // shared-expert H1/G (11.5MB)

  dim3 blk(256);
  auto gemm3 = [&](int mode, const float* A, const float* BT, int M, int N, int K, float* Cf,
                   const float* bias, const float* gv, const float* resid) {
    dim3 grid(N / 128, M / 128);
    switch (mode) {
      case 0: k_gemm3<0><<<grid, blk, 0, stream>>>(A, BT, M, N, K, Cf, bias, gv, resid); break;
      case 2: k_gemm3<2><<<grid, blk, 0, stream>>>(A, BT, M, N, K, Cf, bias, gv, resid); break;
      default: k_gemm3<6><<<grid, blk, 0, stream>>>(A, BT, M, N, K, Cf, bias, gv, resid); break;
    }
  };

  // adaLN modulation vector
  k_adaln_p<<<dim3(MOD6 / 256, 16), blk, 0, stream>>>(adaln_input, W_ada, adap);
  k_adaln_r<<<dim3(MOD6 / 256), blk, 0, stream>>>(adap, b_ada, modv);

  // ---- attention branch (f32-accurate via split-bf16 GEMMs) ----
  k_ln_modf<<<dim3(SEQ), blk, 0, stream>>>(image_tokens, modv, 0, DIMC, xf);
  k_transpose_f<<<dim3(DIMC / 32, DIMC / 32), blk, 0, stream>>>(Wq, wTf, DIMC, DIMC, DIMC);
  gemm3(0, xf, wTf, SEQ, DIMC, DIMC, tf, bq, nullptr, nullptr);
  k_rms_f32<<<dim3(SEQ), blk, 0, stream>>>(tf, q_rms_w, 0.08838834764831845f, qf);
  k_transpose_f<<<dim3(DIMC / 32, DIMC / 32), blk, 0, stream>>>(Wk, wTf, DIMC, DIMC, DIMC);
  gemm3(0, xf, wTf, SEQ, DIMC, DIMC, tf, bk, nullptr, nullptr);
  k_rms_f32<<<dim3(SEQ), blk, 0, stream>>>(tf, k_rms_w, 1.f, kf);
  k_transpose_f<<<dim3(DIMC / 32, DIMC / 32), blk, 0, stream>>>(Wv, wTf, DIMC, DIMC, DIMC);
  gemm3(6, xf, wTf, SEQ, DIMC, DIMC, vtf, bv, nullptr, nullptr);
  k_flash3<<<dim3(SEQ / 64, NHEAD), blk, 0, stream>>>(qf, kf, vtf, aof);
  k_transpose_f<<<dim3(DIMC / 32, DIMC / 32), blk, 0, stream>>>(Wo, wTf, DIMC, DIMC, DIMC);
  gemm3(2, aof, wTf, SEQ, DIMC, DIMC, img, bo, modv + 2 * DIMC, image_tokens);

  // ---- MoE branch (attention buffers now dead; aliases live) ----
  k_ln_mod<<<dim3(SEQ), blk, 0, stream>>>(img, modv, 3 * DIMC, 4 * DIMC, x_act);
  k_gate<<<dim3(SEQ), blk, 0, stream>>>(img, modv, gate_w, comb);
  k_route<<<dim3(1), blk, 0, stream>>>(comb, gidx, cw, Mpad);

  // shared expert FIRST (dense, BK=64; initializes ff with a plain store)
  k_transpose<<<dim3(HSH / 32, DIMC / 32), blk, 0, stream>>>(Ws1, wbufS, DIMC, HSH, HSH, 0, 0);
  k_gemm<1><<<dim3(HSH / 128, SEQ / 128), blk, 0, stream>>>(x_act, wbufS, SEQ, HSH, DIMC, nullptr,
                                                            H1Gs, nullptr);
  k_transpose<<<dim3(HSH / 32, DIMC / 32), blk, 0, stream>>>(Ws3, wbufS, DIMC, HSH, HSH, 0, 0);
  k_gemm<3><<<dim3(HSH / 128, SEQ / 128), blk, 0, stream>>>(x_act, wbufS, SEQ, HSH, DIMC, nullptr,
                                                            H1Gs, H1Gs);
  k_transpose<<<dim3(DIMC / 32, HSH / 32), blk, 0, stream>>>(Ws2, wbufS, HSH, DIMC, DIMC, 0, 0);
  k_gemm<0><<<dim3(DIMC / 128, SEQ / 128), blk, 0, stream>>>(H1Gs, wbufS, SEQ, DIMC, HSH, ff,
                                                             nullptr, nullptr);

  // routed experts, processed in z-batched pairs (top-2 => ~half the dense FLOPs)
  const size_t WE = (size_t)DIMC * HIDC;  // per-expert weight elements
  for (int p = 0; p < 2; ++p) {
    const int e0 = p * 2;
    const int* ge = gidx + e0 * RSTRIDE;
    const float* ce = cw + e0 * RSTRIDE;
    const int* me = Mpad + e0;
    // up-projection 1
    k_transpose<<<dim3(HIDC / 32, DIMC / 32, 2), blk, 0, stream>>>(We1 + (size_t)e0 * WE, wbufE,
                                                                   DIMC, HIDC, HIDC, WE, BZ);
    k_gemmR<0><<<dim3(HIDC / 128, SEQ / 128, 2), blk, 0, stream>>>(x_act, 0, wbufE, BZ, HIDC, DIMC,
                                                                   ge, ce, me, H1G2, CZ, H1G2, nullptr);
    // up-projection 3 + SwiGLU (in-place)
    k_transpose<<<dim3(HIDC / 32, DIMC / 32, 2), blk, 0, stream>>>(We3 + (size_t)e0 * WE, wbufE,
                                                                   DIMC, HIDC, HIDC, WE, BZ);
    k_gemmR<1><<<dim3(HIDC / 128, SEQ / 128, 2), blk, 0, stream>>>(x_act, 0, wbufE, BZ, HIDC, DIMC,
                                                                   ge, ce, me, H1G2, CZ, H1G2, nullptr);
    // down-projection: serialized per expert (concurrent scatter-add to ff would race)
    k_transpose<<<dim3(DIMC / 32, HIDC / 32, 2), blk, 0, stream>>>(We2 + (size_t)e0 * WE, wbufE,
                                                                   HIDC, DIMC, DIMC, WE, BZ);
    for (int z = 0; z < 2; ++z) {
      k_gemmR<2><<<dim3(DIMC / 128, SEQ / 128, 1), blk, 0, stream>>>(
          H1G2 + (size_t)z * CZ, 0, wbufE + (size_t)z * BZ, 0, DIMC, HIDC, gidx + (e0 + z) * RSTRIDE,
          cw + (e0 + z) * RSTRIDE, Mpad + e0 + z, H1G2, 0, H1G2, ff);
    }
  }

  k_final<<<dim3(1024), blk, 0, stream>>>(ff, img, modv, (float*)d_out);
}